// Round 6
// baseline (1888.629 us; speedup 1.0000x reference)
//
#include <hip/hip_runtime.h>
#include <math.h>

typedef unsigned short u16;
typedef short s16x8 __attribute__((ext_vector_type(8)));
typedef float f32x4 __attribute__((ext_vector_type(4)));

#define BM 128
#define BN 128
#define BK 32

__device__ __forceinline__ u16 f2bf(float f) {
    union { float f; unsigned u; } v; v.f = f;
    unsigned u = v.u + 0x7FFFu + ((v.u >> 16) & 1u);
    return (u16)(u >> 16);
}
__device__ __forceinline__ float bf2f(u16 u) {
    union { unsigned u; float f; } v; v.u = ((unsigned)u) << 16; return v.f;
}

__device__ __forceinline__ void g2lds16(const void* g, void* l) {
    __builtin_amdgcn_global_load_lds(
        (const __attribute__((address_space(1))) void*)g,
        (__attribute__((address_space(3))) void*)l, 16, 0, 0);
}

enum { E_F32 = 0, E_BF16 = 1, E_QKV = 2, E_SMIX = 3, E_Y = 5 };

// ============================================================================
// Fused S-GEMM + dual online row-softmax + Pre(logaddexp mix) + A2-transpose.
// Grid (32, 1, G), block 512 (8 waves, 2m x 4n). Per block: 64 rows x all 2048.
// Writes A1 [2048][2048] bf16, A2t (transposed) bf16, Pre bf16. S stays f32.
// Q tiles swizzled in LDS (granule ^= row&7, pre-swizzled global src, rule 21).
// ============================================================================
__global__ __launch_bounds__(512) void fused_s(
    const u16* __restrict__ Q1, const u16* __restrict__ K1,
    const u16* __restrict__ Q2, const u16* __restrict__ K2,
    u16* __restrict__ A1o, u16* __restrict__ A2to, u16* __restrict__ Preo)
{
    __shared__ __align__(16) u16 Qs[2][4096];
    __shared__ __align__(16) u16 Ks[2][16384];
    __shared__ float stats[2][64][2];   // running m, l (then 1/l)
    __shared__ float part[2][4][64];    // per-wn partials (max, then sum)
    __shared__ float newm[2][64];
    __shared__ __align__(16) u16 bounce[64 * 264];  // pad: stride 528B, 16B-aligned

    const int z = blockIdx.z;
    const long ND = 2048L * 64;
    const long NNl = 2048L * 2048;
    const u16* Q1z = Q1 + z * ND;
    const u16* K1z = K1 + z * ND;
    const u16* Q2z = Q2 + z * ND;
    const u16* K2z = K2 + z * ND;
    u16* A1p  = A1o  + z * NNl;
    u16* A2tp = A2to + z * NNl;
    u16* Prep = Preo + z * NNl;

    const int t = threadIdx.x;
    const int lane = t & 63, wid = t >> 6;
    const int wm = wid >> 2, wn = wid & 3;
    const int fr = lane & 15, g4 = lane >> 4;
    const int mb = blockIdx.x * 64;

    // stage Q tiles once (64 rows x 64 k each)
    {
        const int r = t >> 3;
        const int gsw = ((t & 7) ^ (r & 7)) * 8;
        g2lds16(Q1z + (long)(mb + r) * 64 + gsw, &Qs[0][t * 8]);
        g2lds16(Q2z + (long)(mb + r) * 64 + gsw, &Qs[1][t * 8]);
    }
    if (t < 128) { stats[t >> 6][t & 63][0] = -3.0e38f; stats[t >> 6][t & 63][1] = 0.f; }
    __syncthreads();

    auto stageK = [&](int n0) {
#pragma unroll
        for (int s = 0; s < 4; ++s) {
            const int row = s * 64 + (t >> 3);
            const int gsw = ((t & 7) ^ (row & 7)) * 8;
            g2lds16(K1z + (long)(n0 + row) * 64 + gsw, &Ks[0][s * 4096 + t * 8]);
            g2lds16(K2z + (long)(n0 + row) * 64 + gsw, &Ks[1][s * 4096 + t * 8]);
        }
    };

    auto computeS = [&](f32x4 acc[2][2][4]) {
#pragma unroll
        for (int st = 0; st < 2; ++st)
#pragma unroll
            for (int fm = 0; fm < 2; ++fm)
#pragma unroll
                for (int fn = 0; fn < 4; ++fn) acc[st][fm][fn] = (f32x4){0.f, 0.f, 0.f, 0.f};
#pragma unroll
        for (int s = 0; s < 2; ++s) {
            const int gr = ((s * 4 + g4) ^ (fr & 7)) * 8;
            s16x8 a[2][2], b[2][4];
#pragma unroll
            for (int fm = 0; fm < 2; ++fm) {
                a[0][fm] = *(const s16x8*)(const void*)(&Qs[0][(wm * 32 + fm * 16 + fr) * 64 + gr]);
                a[1][fm] = *(const s16x8*)(const void*)(&Qs[1][(wm * 32 + fm * 16 + fr) * 64 + gr]);
            }
#pragma unroll
            for (int fn = 0; fn < 4; ++fn) {
                b[0][fn] = *(const s16x8*)(const void*)(&Ks[0][(wn * 64 + fn * 16 + fr) * 64 + gr]);
                b[1][fn] = *(const s16x8*)(const void*)(&Ks[1][(wn * 64 + fn * 16 + fr) * 64 + gr]);
            }
#pragma unroll
            for (int st = 0; st < 2; ++st)
#pragma unroll
                for (int fm = 0; fm < 2; ++fm)
#pragma unroll
                    for (int fn = 0; fn < 4; ++fn)
                        acc[st][fm][fn] = __builtin_amdgcn_mfma_f32_16x16x32_bf16(
                            a[st][fm], b[st][fn], acc[st][fm][fn], 0, 0, 0);
        }
    };

    // ---------------- pass 1: online stats ----------------
    for (int n0 = 0; n0 < 2048; n0 += 256) {
        stageK(n0);
        __syncthreads();
        f32x4 acc[2][2][4];
        computeS(acc);
#pragma unroll
        for (int st = 0; st < 2; ++st)
#pragma unroll
            for (int fm = 0; fm < 2; ++fm)
#pragma unroll
                for (int r = 0; r < 4; ++r) {
                    float mx = acc[st][fm][0][r];
#pragma unroll
                    for (int fn = 1; fn < 4; ++fn) mx = fmaxf(mx, acc[st][fm][fn][r]);
                    mx = fmaxf(mx, __shfl_xor(mx, 1));
                    mx = fmaxf(mx, __shfl_xor(mx, 2));
                    mx = fmaxf(mx, __shfl_xor(mx, 4));
                    mx = fmaxf(mx, __shfl_xor(mx, 8));
                    if (fr == 0) part[st][wn][wm * 32 + fm * 16 + g4 * 4 + r] = mx;
                }
        __syncthreads();
        if (t < 128) {
            const int st = t >> 6, row = t & 63;
            const float mt = fmaxf(fmaxf(part[st][0][row], part[st][1][row]),
                                   fmaxf(part[st][2][row], part[st][3][row]));
            newm[st][row] = fmaxf(stats[st][row][0], mt);
        }
        __syncthreads();
#pragma unroll
        for (int st = 0; st < 2; ++st)
#pragma unroll
            for (int fm = 0; fm < 2; ++fm)
#pragma unroll
                for (int r = 0; r < 4; ++r) {
                    const int row = wm * 32 + fm * 16 + g4 * 4 + r;
                    const float nm = newm[st][row];
                    float ps = 0.f;
#pragma unroll
                    for (int fn = 0; fn < 4; ++fn) ps += __expf(acc[st][fm][fn][r] - nm);
                    ps += __shfl_xor(ps, 1);
                    ps += __shfl_xor(ps, 2);
                    ps += __shfl_xor(ps, 4);
                    ps += __shfl_xor(ps, 8);
                    if (fr == 0) part[st][wn][row] = ps;
                }
        __syncthreads();
        if (t < 128) {
            const int st = t >> 6, row = t & 63;
            const float nm = newm[st][row];
            const float lt = part[st][0][row] + part[st][1][row] +
                             part[st][2][row] + part[st][3][row];
            stats[st][row][1] = stats[st][row][1] * __expf(stats[st][row][0] - nm) + lt;
            stats[st][row][0] = nm;
        }
        __syncthreads();
    }
    if (t < 128) stats[t >> 6][t & 63][1] = 1.f / stats[t >> 6][t & 63][1];
    __syncthreads();

    // ---------------- pass 2: emit A1, Pre, A2t ----------------
    for (int n0 = 0; n0 < 2048; n0 += 256) {
        stageK(n0);
        __syncthreads();
        f32x4 acc[2][2][4];
        computeS(acc);

        // A1
#pragma unroll
        for (int fm = 0; fm < 2; ++fm)
#pragma unroll
            for (int r = 0; r < 4; ++r) {
                const int row = wm * 32 + fm * 16 + g4 * 4 + r;
                const float m1 = stats[0][row][0], li1 = stats[0][row][1];
#pragma unroll
                for (int fn = 0; fn < 4; ++fn)
                    bounce[row * 264 + wn * 64 + fn * 16 + fr] =
                        f2bf(__expf(acc[0][fm][fn][r] - m1) * li1);
            }
        __syncthreads();
        {
            const int row = t >> 3, c0 = (t & 7) * 32;
#pragma unroll
            for (int s = 0; s < 4; ++s)
                *(s16x8*)(void*)(A1p + (long)(mb + row) * 2048 + n0 + c0 + s * 8) =
                    *(const s16x8*)(const void*)(&bounce[row * 264 + c0 + s * 8]);
        }
        __syncthreads();

        // Pre = 0.5*S1 + 0.75*S2 + 0.5*logaddexp(S1,S2)
#pragma unroll
        for (int fm = 0; fm < 2; ++fm)
#pragma unroll
            for (int r = 0; r < 4; ++r) {
                const int row = wm * 32 + fm * 16 + g4 * 4 + r;
#pragma unroll
                for (int fn = 0; fn < 4; ++fn) {
                    const float s1 = acc[0][fm][fn][r];
                    const float s2 = acc[1][fm][fn][r];
                    const float lae = fmaxf(s1, s2) + log1pf(__expf(-fabsf(s1 - s2)));
                    bounce[row * 264 + wn * 64 + fn * 16 + fr] =
                        f2bf(0.5f * s1 + 0.75f * s2 + 0.5f * lae);
                }
            }
        __syncthreads();
        {
            const int row = t >> 3, c0 = (t & 7) * 32;
#pragma unroll
            for (int s = 0; s < 4; ++s)
                *(s16x8*)(void*)(Prep + (long)(mb + row) * 2048 + n0 + c0 + s * 8) =
                    *(const s16x8*)(const void*)(&bounce[row * 264 + c0 + s * 8]);
        }
        __syncthreads();

        // A2 -> transposed write
#pragma unroll
        for (int fm = 0; fm < 2; ++fm)
#pragma unroll
            for (int r = 0; r < 4; ++r) {
                const int row = wm * 32 + fm * 16 + g4 * 4 + r;
                const float m2 = stats[1][row][0], li2 = stats[1][row][1];
#pragma unroll
                for (int fn = 0; fn < 4; ++fn)
                    bounce[row * 264 + wn * 64 + fn * 16 + fr] =
                        f2bf(__expf(acc[1][fm][fn][r] - m2) * li2);
            }
        __syncthreads();
        {
            const int nloc = t & 255, mseg = t >> 8;
#pragma unroll
            for (int q = 0; q < 4; ++q) {
                s16x8 v;
#pragma unroll
                for (int e = 0; e < 8; ++e)
                    v[e] = (short)bounce[(mseg * 32 + q * 8 + e) * 264 + nloc];
                *(s16x8*)(void*)(A2tp + (long)(n0 + nloc) * 2048 + mb + mseg * 32 + q * 8) = v;
            }
        }
        __syncthreads();
    }
}

// ============================================================================
// 256x256-tile, BK=64, 8-wave counted-vmcnt pipelined GEMM (chain GEMMs).
// ============================================================================
template<int EPI>
__global__ __launch_bounds__(512) void gemm256_nt(
    const u16* __restrict__ A, const u16* __restrict__ B,
    long sAz, long sBz, int lda, int ldb, int K,
    u16* __restrict__ outb, u16* __restrict__ outb2,
    const u16* __restrict__ aux1b, long sOz, int ldc)
{
    __shared__ __align__(16) u16 As[2][2][8192];
    __shared__ __align__(16) u16 Bs[2][2][8192];

    const int z   = blockIdx.z;
    const u16* Ab = A + (long)z * sAz;
    const u16* Bb = B + (long)z * sBz;
    const int t    = threadIdx.x;
    const int lane = t & 63;
    const int wid  = t >> 6;
    const int wm   = wid >> 2;
    const int wn   = wid & 3;
    const int fr   = lane & 15;
    const int g4   = lane >> 4;
    const int m0   = blockIdx.x * 256;
    const int n0   = blockIdx.y * 256;

    const int r0 = t >> 3;
    const int xc = ((t & 7) ^ (r0 & 7)) * 8;
    const u16* pA0 = Ab + (long)(m0 + r0) * lda + xc;
    const u16* pA1 = Ab + (long)(m0 + 64 + r0) * lda + xc;
    const u16* pA2 = Ab + (long)(m0 + 128 + r0) * lda + xc;
    const u16* pA3 = Ab + (long)(m0 + 192 + r0) * lda + xc;
    const u16* pB0 = Bb + (long)(n0 + r0) * ldb + xc;
    const u16* pB1 = Bb + (long)(n0 + 64 + r0) * ldb + xc;
    const u16* pB2 = Bb + (long)(n0 + 128 + r0) * ldb + xc;
    const u16* pB3 = Bb + (long)(n0 + 192 + r0) * ldb + xc;
    const int d0 = t * 8;
    const int d1 = t * 8 + 4096;

#define STAGE256(d, kk)                        \
    do {                                       \
        g2lds16(pA0 + (kk), &As[d][0][d0]);    \
        g2lds16(pA1 + (kk), &As[d][0][d1]);    \
        g2lds16(pA2 + (kk), &As[d][1][d0]);    \
        g2lds16(pA3 + (kk), &As[d][1][d1]);    \
        g2lds16(pB0 + (kk), &Bs[d][0][d0]);    \
        g2lds16(pB1 + (kk), &Bs[d][0][d1]);    \
        g2lds16(pB2 + (kk), &Bs[d][1][d0]);    \
        g2lds16(pB3 + (kk), &Bs[d][1][d1]);    \
    } while (0)

    const int swz  = fr & 7;
    const int rbS0 = fr * 64 + ((g4 ^ swz) * 8);
    const int rbS1 = fr * 64 + (((4 + g4) ^ swz) * 8);

    f32x4 acc[8][4];
#pragma unroll
    for (int i = 0; i < 8; ++i)
#pragma unroll
        for (int j = 0; j < 4; ++j) acc[i][j] = (f32x4){0.f, 0.f, 0.f, 0.f};

    STAGE256(0, 0);
    const int NT = K >> 6;
    for (int T = 0; T < NT; ++T) {
        const int d = T & 1;
        if (T + 1 < NT) {
            STAGE256(d ^ 1, (T + 1) << 6);
            asm volatile("s_waitcnt vmcnt(8)" ::: "memory");
        } else {
            asm volatile("s_waitcnt vmcnt(0)" ::: "memory");
        }
        __builtin_amdgcn_s_barrier();
        __builtin_amdgcn_sched_barrier(0);
        __builtin_amdgcn_s_setprio(1);
        {
            const u16* Abase = &As[d][wm][0];
            const u16* Bbase = &Bs[d][wn >> 1][(wn & 1) * 4096];
            s16x8 bv[4][2];
#pragma unroll
            for (int fn = 0; fn < 4; ++fn) {
                bv[fn][0] = *(const s16x8*)(const void*)(Bbase + fn * 1024 + rbS0);
                bv[fn][1] = *(const s16x8*)(const void*)(Bbase + fn * 1024 + rbS1);
            }
#pragma unroll
            for (int h = 0; h < 2; ++h) {
                s16x8 av[4][2];
#pragma unroll
                for (int fm = 0; fm < 4; ++fm) {
                    av[fm][0] = *(const s16x8*)(const void*)(Abase + (h * 4 + fm) * 1024 + rbS0);
                    av[fm][1] = *(const s16x8*)(const void*)(Abase + (h * 4 + fm) * 1024 + rbS1);
                }
#pragma unroll
                for (int fm = 0; fm < 4; ++fm)
#pragma unroll
                    for (int fn = 0; fn < 4; ++fn) {
                        acc[h * 4 + fm][fn] = __builtin_amdgcn_mfma_f32_16x16x32_bf16(
                            av[fm][0], bv[fn][0], acc[h * 4 + fm][fn], 0, 0, 0);
                        acc[h * 4 + fm][fn] = __builtin_amdgcn_mfma_f32_16x16x32_bf16(
                            av[fm][1], bv[fn][1], acc[h * 4 + fm][fn], 0, 0, 0);
                    }
            }
        }
        __builtin_amdgcn_s_setprio(0);
        __builtin_amdgcn_sched_barrier(0);
        __builtin_amdgcn_s_barrier();
    }
#undef STAGE256

#pragma unroll
    for (int fm = 0; fm < 8; ++fm) {
#pragma unroll
        for (int r = 0; r < 4; ++r) {
            const int gm = m0 + wm * 128 + fm * 16 + g4 * 4 + r;
#pragma unroll
            for (int fn = 0; fn < 4; ++fn) {
                const int gn = n0 + wn * 64 + fn * 16 + fr;
                const float v = acc[fm][fn][r];
                const long off = (long)z * sOz + (long)gm * ldc + gn;
                if (EPI == E_BF16) {
                    outb[off] = f2bf(v);
                } else {  // E_SMIX
                    const float pre = bf2f(aux1b[off]);
                    outb[off]  = f2bf(pre + 0.5f * __logf(v + 1e-6f));
                    outb2[off] = f2bf(v);
                }
            }
        }
    }
}

// ============================================================================
// 128x128-tile 2-phase GEMM (QKV / small matmuls).
// ============================================================================
template<int EPI>
__global__ __launch_bounds__(256) void gemm_nt(
    const u16* __restrict__ A, const u16* __restrict__ B,
    long sAz, long sBz, int lda, int ldb,
    int M, int Ncols, int K,
    float* __restrict__ outf, u16* __restrict__ outb,
    u16* __restrict__ outb2, u16* __restrict__ outb3,
    const float* __restrict__ aux1f, const u16* __restrict__ aux1b,
    const float* __restrict__ chainp,
    long sOz, int ldc, float scale, int zbase)
{
    __shared__ __align__(16) u16 As[2][BM * BK];
    __shared__ __align__(16) u16 Bs[2][BN * BK];

    const int z    = blockIdx.z;
    const u16* Ab  = A + (long)z * sAz;
    const u16* Bb  = B + (long)z * sBz;
    const int tid  = threadIdx.x;
    const int lane = tid & 63;
    const int wid  = tid >> 6;
    const int m0   = blockIdx.x * BM;
    const int n0   = blockIdx.y * BN;
    const int wr   = (wid >> 1) * 64;
    const int wc   = (wid & 1) * 64;

    f32x4 zero = {0.f, 0.f, 0.f, 0.f};
    f32x4 acc[4][4];
#pragma unroll
    for (int i = 0; i < 4; ++i)
#pragma unroll
        for (int j = 0; j < 4; ++j) acc[i][j] = zero;

    const int srow = tid >> 2;
    const int scol = (tid & 3) * 8;
    int bn0 = n0 + srow;      if (bn0 > Ncols - 1) bn0 = Ncols - 1;
    int bn1 = n0 + 64 + srow; if (bn1 > Ncols - 1) bn1 = Ncols - 1;
    const u16* gA0 = Ab + (long)(m0 + srow) * lda + scol;
    const u16* gA1 = Ab + (long)(m0 + 64 + srow) * lda + scol;
    const u16* gB0 = Bb + (long)bn0 * ldb + scol;
    const u16* gB1 = Bb + (long)bn1 * ldb + scol;

    const int kq = (lane >> 4) * 8;
    const int fr = lane & 15;

#define STAGE(buf, kk)                                  \
    do {                                                \
        g2lds16(gA0 + (kk), &As[buf][tid * 8]);         \
        g2lds16(gA1 + (kk), &As[buf][2048 + tid * 8]);  \
        g2lds16(gB0 + (kk), &Bs[buf][tid * 8]);         \
        g2lds16(gB1 + (kk), &Bs[buf][2048 + tid * 8]);  \
    } while (0)

    STAGE(0, 0);
    __syncthreads();
    int cur = 0;
    for (int k0 = 0; k0 < K; k0 += BK) {
        if (k0 + BK < K) STAGE(cur ^ 1, k0 + BK);
        s16x8 af[4], bfr[4];
#pragma unroll
        for (int i = 0; i < 4; ++i)
            af[i] = *(const s16x8*)(const void*)(&As[cur][(wr + i * 16 + fr) * BK + kq]);
#pragma unroll
        for (int j = 0; j < 4; ++j)
            bfr[j] = *(const s16x8*)(const void*)(&Bs[cur][(wc + j * 16 + fr) * BK + kq]);
#pragma unroll
        for (int i = 0; i < 4; ++i)
#pragma unroll
            for (int j = 0; j < 4; ++j)
                acc[i][j] = __builtin_amdgcn_mfma_f32_16x16x32_bf16(af[i], bfr[j], acc[i][j], 0, 0, 0);
        __syncthreads();
        cur ^= 1;
    }
#undef STAGE

    const int rbase = (lane >> 4) * 4;
    const int cidx  = lane & 15;
    float wgate = 0.f;
    if (EPI == E_Y) wgate = 1.f / (1.f + __expf(-chainp[0]));

#pragma unroll
    for (int i = 0; i < 4; ++i) {
#pragma unroll
        for (int r = 0; r < 4; ++r) {
            const int gm = m0 + wr + i * 16 + rbase + r;
#pragma unroll
            for (int j = 0; j < 4; ++j) {
                const int gn = n0 + wc + j * 16 + cidx;
                const float v = acc[i][j][r];
                if (EPI == E_F32) {
                    if (gn < Ncols) outf[(long)z * sOz + (long)gm * ldc + gn] = v * scale;
                } else if (EPI == E_BF16) {
                    if (gn < Ncols) outb[(long)z * sOz + (long)gm * ldc + gn] = f2bf(v * scale);
                } else if (EPI == E_QKV) {
                    const int b_ = gm >> 11, ntok = gm & 2047;
                    const int which = gn >> 9, h = (gn & 511) >> 6, d = gn & 63;
                    const long bh = (long)(b_ * 8 + h);
                    const u16 bv = f2bf(which == 0 ? v * scale : v);
                    if (which == 0)       outb [(bh * 2048 + ntok) * 64 + d] = bv;
                    else if (which == 1)  outb2[(bh * 2048 + ntok) * 64 + d] = bv;
                    else                  outb3[(bh * 64 + d) * 2048 + ntok] = bv;
                } else if (EPI == E_SMIX) {
                    const long off = (long)z * sOz + (long)gm * ldc + gn;
                    const float pre = bf2f(aux1b[off]);
                    outb[off]  = f2bf(pre + 0.5f * __logf(v + 1e-6f));
                    outb2[off] = f2bf(v);
                } else if (EPI == E_Y) {
                    if (gn < Ncols) {
                        const float yv = v + wgate * aux1f[(long)z * sOz + (long)gm * 64 + gn];
                        const int zg = zbase + z;
                        const int b_ = zg >> 3, h = zg & 7;
                        outb[((long)(b_ * 2048 + gm)) * 512 + h * 64 + gn] = f2bf(yv);
                    }
                }
            }
        }
    }
}

__global__ __launch_bounds__(256) void cvt_f32_bf16(const float* __restrict__ in,
                                                    u16* __restrict__ out, long n) {
    long i = (long)blockIdx.x * 256 + threadIdx.x;
    if (i < n) out[i] = f2bf(in[i]);
}

// in: [R][C] f32  ->  out: [C][R] bf16
__global__ __launch_bounds__(256) void cvt_transpose(const float* __restrict__ in,
                                                     u16* __restrict__ out, int R, int C) {
    long i = (long)blockIdx.x * 256 + threadIdx.x;
    if (i < (long)R * C) {
        int c = (int)(i / R), r = (int)(i % R);
        out[i] = f2bf(in[(long)r * C + c]);
    }
}

// One block per row (2048 bf16): A = softmax(S).
__global__ __launch_bounds__(256) void row_softmax_bf(
    const u16* __restrict__ S, u16* __restrict__ A)
{
    const long row = blockIdx.x;
    const u16* p = S + row * 2048;
    const int t = threadIdx.x;
    s16x8 xv = *(const s16x8*)(const void*)(p + t * 8);
    float x[8];
#pragma unroll
    for (int e = 0; e < 8; ++e) x[e] = bf2f((u16)xv[e]);
    float m = x[0];
#pragma unroll
    for (int e = 1; e < 8; ++e) m = fmaxf(m, x[e]);
#pragma unroll
    for (int off = 32; off >= 1; off >>= 1) m = fmaxf(m, __shfl_xor(m, off));
    __shared__ float red[8];
    if ((t & 63) == 0) red[t >> 6] = m;
    __syncthreads();
    m = fmaxf(fmaxf(red[0], red[1]), fmaxf(red[2], red[3]));
    float s = 0.f, ee[8];
#pragma unroll
    for (int e = 0; e < 8; ++e) { ee[e] = __expf(x[e] - m); s += ee[e]; }
#pragma unroll
    for (int off = 32; off >= 1; off >>= 1) s += __shfl_xor(s, off);
    if ((t & 63) == 0) red[4 + (t >> 6)] = s;
    __syncthreads();
    s = red[4] + red[5] + red[6] + red[7];
    const float inv = 1.f / s;
    s16x8 o;
#pragma unroll
    for (int e = 0; e < 8; ++e) o[e] = (short)f2bf(ee[e] * inv);
    *(s16x8*)(void*)(A + row * 2048 + t * 8) = o;
}

extern "C" void kernel_launch(void* const* d_in, const int* in_sizes, int n_in,
                              void* d_out, int out_size, void* d_ws, size_t ws_size,
                              hipStream_t stream) {
    const float* x  = (const float*)d_in[0];
    const float* W1 = (const float*)d_in[1];
    const float* W2 = (const float*)d_in[2];
    const float* Wp = (const float*)d_in[3];
    const float* ch = (const float*)d_in[4];

    const int Bq = 2, N = 2048, D = 512, dk = 64, Z = 16;
    const long NN = (long)N * N;
    const long ND = (long)N * dk;
    (void)in_sizes; (void)n_in; (void)out_size;

    size_t ws_avail = ws_size ? ws_size : (size_t)-1;

    char* w = (char*)d_ws;
    size_t off = 0;
    auto alc = [&](size_t bytes) -> void* {
        void* p = w + off;
        off += (bytes + 255) & ~(size_t)255;
        return p;
    };

    // ---- persistent (~36 MiB) ----
    u16* xb   = (u16*)alc((long)Bq * N * D * 2);
    u16* W1t  = (u16*)alc((long)3 * D * D * 2);
    u16* W2t  = (u16*)alc((long)3 * D * D * 2);
    u16* Wpt  = (u16*)alc((long)D * D * 2);
    u16* Q1   = (u16*)alc(Z * ND * 2);
    u16* K1   = (u16*)alc(Z * ND * 2);
    u16* V1t  = (u16*)alc(Z * ND * 2);
    u16* Q2   = (u16*)alc(Z * ND * 2);
    u16* K2   = (u16*)alc(Z * ND * 2);
    u16* V2t  = (u16*)alc(Z * ND * 2);
    u16* y    = (u16*)alc((long)Bq * N * D * 2);
    const size_t persist = off;

    const size_t perz = 4 * (size_t)(NN * 2) + (size_t)(ND * 4) + 4096;
    int G = 16;
    while (G > 1 && persist + (size_t)G * perz + 65536 > ws_avail) G >>= 1;

    u16*  S1b = (u16*)alc((size_t)G * NN * 2);   // Pre -> Smix
    u16*  S2b = (u16*)alc((size_t)G * NN * 2);   // A2t
    u16*  A1b = (u16*)alc((size_t)G * NN * 2);   // A1 -> C2
    u16*  C1b = (u16*)alc((size_t)G * NN * 2);   // C1 -> final A
    float* yc = (float*)alc((size_t)G * ND * 4);

    const dim3 blk(256);
    const float iscale = 0.125f;  // 1/sqrt(64)

    cvt_f32_bf16<<<(unsigned)(((long)Bq * N * D + 255) / 256), blk, 0, stream>>>(x, xb, (long)Bq * N * D);
    cvt_transpose<<<(3 * D * D + 255) / 256, blk, 0, stream>>>(W1, W1t, D, 3 * D);
    cvt_transpose<<<(3 * D * D + 255) / 256, blk, 0, stream>>>(W2, W2t, D, 3 * D);
    cvt_transpose<<<(D * D + 255) / 256, blk, 0, stream>>>(Wp, Wpt, D, D);

    gemm_nt<E_QKV><<<dim3(32, 12, 1), blk, 0, stream>>>(
        xb, W1t, 0L, 0L, D, D, Bq * N, 3 * D, D,
        nullptr, Q1, K1, V1t, nullptr, nullptr, nullptr, 0L, 0, iscale, 0);
    gemm_nt<E_QKV><<<dim3(32, 12, 1), blk, 0, stream>>>(
        xb, W2t, 0L, 0L, D, D, Bq * N, 3 * D, D,
        nullptr, Q2, K2, V2t, nullptr, nullptr, nullptr, 0L, 0, iscale, 0);

    for (int zb = 0; zb < Z; zb += G) {
        const u16* Q1z = Q1 + (long)zb * ND;
        const u16* K1z = K1 + (long)zb * ND;
        const u16* V1z = V1t + (long)zb * ND;
        const u16* Q2z = Q2 + (long)zb * ND;
        const u16* K2z = K2 + (long)zb * ND;
        const u16* V2z = V2t + (long)zb * ND;

        // fused: A1 -> A1b ; A2t -> S2b ; Pre -> S1b
        fused_s<<<dim3(32, 1, G), dim3(512), 0, stream>>>(
            Q1z, K1z, Q2z, K2z, A1b, S2b, S1b);

        // C1 = A1 @ A2 -> C1b
        gemm256_nt<E_BF16><<<dim3(8, 8, G), dim3(512), 0, stream>>>(
            A1b, S2b, NN, NN, N, N, N,
            C1b, nullptr, nullptr, NN, N);
        // C2 = C1 @ A2 ; Smix = Pre + 0.5*log(C2+eps) -> S1b ; C2 -> A1b
        gemm256_nt<E_SMIX><<<dim3(8, 8, G), dim3(512), 0, stream>>>(
            C1b, S2b, NN, NN, N, N, N,
            S1b, A1b, S1b, NN, N);
        // A = softmax(Smix) -> C1b
        row_softmax_bf<<<G * N, blk, 0, stream>>>(S1b, C1b);

        // y_chain = C2 @ v2  (f32 [z][N][64])
        gemm_nt<E_F32><<<dim3(16, 1, G), blk, 0, stream>>>(
            A1b, V2z, NN, ND, N, N, N, dk, N,
            yc, nullptr, nullptr, nullptr, nullptr, nullptr, nullptr, ND, dk, 1.f, 0);
        // y = A @ v1 + sigmoid(chain)*y_chain  -> bf16 [B,N,D]
        gemm_nt<E_Y><<<dim3(16, 1, G), blk, 0, stream>>>(
            C1b, V1z, NN, ND, N, N, N, dk, N,
            nullptr, y, nullptr, nullptr, yc, nullptr, ch, ND, dk, 1.f, zb);
    }

    // out = y @ Wproj   (f32)
    gemm_nt<E_F32><<<dim3(32, 4, 1), blk, 0, stream>>>(
        y, Wpt, 0L, 0L, D, D, Bq * N, D, D,
        (float*)d_out, nullptr, nullptr, nullptr, nullptr, nullptr, nullptr, 0L, D, 1.f, 0);
}

// Round 7
// 1559.994 us; speedup vs baseline: 1.2107x; 1.2107x over previous
//
#include <hip/hip_runtime.h>
#include <math.h>

typedef unsigned short u16;
typedef short s16x8 __attribute__((ext_vector_type(8)));
typedef float f32x4 __attribute__((ext_vector_type(4)));

#define BM 128
#define BN 128
#define BK 32

__device__ __forceinline__ u16 f2bf(float f) {
    union { float f; unsigned u; } v; v.f = f;
    unsigned u = v.u + 0x7FFFu + ((v.u >> 16) & 1u);
    return (u16)(u >> 16);
}
__device__ __forceinline__ float bf2f(u16 u) {
    union { unsigned u; float f; } v; v.u = ((unsigned)u) << 16; return v.f;
}

__device__ __forceinline__ void g2lds16(const void* g, void* l) {
    __builtin_amdgcn_global_load_lds(
        (const __attribute__((address_space(1))) void*)g,
        (__attribute__((address_space(3))) void*)l, 16, 0, 0);
}

enum { E_F32 = 0, E_BF16 = 1, E_QKV = 2, E_SMIX = 3, E_Y = 5 };

// ============================================================================
// 256x256-tile, BK=64, 8-wave, counted-vmcnt + fine 4-phase interleave.
// Per iter T: STAGE(T+1) -> vmcnt(8) -> barrier -> 4 x {ds_read subtile ->
// barrier -> lgkmcnt(0) -> setprio 16-MFMA -> barrier}.  LDS XOR-swizzled.
// ============================================================================
template<int EPI>
__global__ __launch_bounds__(512) void gemm256_nt(
    const u16* __restrict__ A, const u16* __restrict__ B,
    long sAz, long sBz, int lda, int ldb, int K,
    u16* __restrict__ outb, u16* __restrict__ outb2,
    const u16* __restrict__ aux1b, long sOz, int ldc)
{
    __shared__ __align__(16) u16 As[2][2][8192];
    __shared__ __align__(16) u16 Bs[2][2][8192];

    const int z   = blockIdx.z;
    const u16* Ab = A + (long)z * sAz;
    const u16* Bb = B + (long)z * sBz;
    const int t    = threadIdx.x;
    const int lane = t & 63;
    const int wid  = t >> 6;
    const int wm   = wid >> 2;
    const int wn   = wid & 3;
    const int fr   = lane & 15;
    const int g4   = lane >> 4;
    const int m0   = blockIdx.x * 256;
    const int n0   = blockIdx.y * 256;

    const int r0 = t >> 3;
    const int xc = ((t & 7) ^ (r0 & 7)) * 8;
    const u16* pA0 = Ab + (long)(m0 + r0) * lda + xc;
    const u16* pA1 = Ab + (long)(m0 + 64 + r0) * lda + xc;
    const u16* pA2 = Ab + (long)(m0 + 128 + r0) * lda + xc;
    const u16* pA3 = Ab + (long)(m0 + 192 + r0) * lda + xc;
    const u16* pB0 = Bb + (long)(n0 + r0) * ldb + xc;
    const u16* pB1 = Bb + (long)(n0 + 64 + r0) * ldb + xc;
    const u16* pB2 = Bb + (long)(n0 + 128 + r0) * ldb + xc;
    const u16* pB3 = Bb + (long)(n0 + 192 + r0) * ldb + xc;
    const int d0 = t * 8;
    const int d1 = t * 8 + 4096;

#define STAGE256(d, kk)                        \
    do {                                       \
        g2lds16(pA0 + (kk), &As[d][0][d0]);    \
        g2lds16(pA1 + (kk), &As[d][0][d1]);    \
        g2lds16(pA2 + (kk), &As[d][1][d0]);    \
        g2lds16(pA3 + (kk), &As[d][1][d1]);    \
        g2lds16(pB0 + (kk), &Bs[d][0][d0]);    \
        g2lds16(pB1 + (kk), &Bs[d][0][d1]);    \
        g2lds16(pB2 + (kk), &Bs[d][1][d0]);    \
        g2lds16(pB3 + (kk), &Bs[d][1][d1]);    \
    } while (0)

#define PH_OPEN()                                                   \
    __builtin_amdgcn_s_barrier();                                   \
    asm volatile("s_waitcnt lgkmcnt(0)" ::: "memory");              \
    __builtin_amdgcn_sched_barrier(0);                              \
    __builtin_amdgcn_s_setprio(1)

#define PH_CLOSE()                                                  \
    __builtin_amdgcn_s_setprio(0);                                  \
    __builtin_amdgcn_sched_barrier(0);                              \
    __builtin_amdgcn_s_barrier()

    const int swz  = fr & 7;
    const int rbS0 = fr * 64 + ((g4 ^ swz) * 8);
    const int rbS1 = fr * 64 + (((4 + g4) ^ swz) * 8);

    f32x4 acc[8][4];
#pragma unroll
    for (int i = 0; i < 8; ++i)
#pragma unroll
        for (int j = 0; j < 4; ++j) acc[i][j] = (f32x4){0.f, 0.f, 0.f, 0.f};

    STAGE256(0, 0);
    const int NT = K >> 6;
    for (int T = 0; T < NT; ++T) {
        const int d = T & 1;
        if (T + 1 < NT) {
            STAGE256(d ^ 1, (T + 1) << 6);
            asm volatile("s_waitcnt vmcnt(8)" ::: "memory");
        } else {
            asm volatile("s_waitcnt vmcnt(0)" ::: "memory");
        }
        __builtin_amdgcn_s_barrier();   // all waves' tile-T loads visible

        const u16* Abase = &As[d][wm][0];
        const u16* Bbase = &Bs[d][wn >> 1][(wn & 1) * 4096];

        // ---- phase 0: B all + A fm{0,1} ----
        s16x8 bv[4][2];
#pragma unroll
        for (int fn = 0; fn < 4; ++fn) {
            bv[fn][0] = *(const s16x8*)(const void*)(Bbase + fn * 1024 + rbS0);
            bv[fn][1] = *(const s16x8*)(const void*)(Bbase + fn * 1024 + rbS1);
        }
#pragma unroll
        for (int p = 0; p < 4; ++p) {
            s16x8 av[2][2];
#pragma unroll
            for (int q = 0; q < 2; ++q) {
                av[q][0] = *(const s16x8*)(const void*)(Abase + (2 * p + q) * 1024 + rbS0);
                av[q][1] = *(const s16x8*)(const void*)(Abase + (2 * p + q) * 1024 + rbS1);
            }
            PH_OPEN();
#pragma unroll
            for (int q = 0; q < 2; ++q)
#pragma unroll
                for (int fn = 0; fn < 4; ++fn) {
                    acc[2 * p + q][fn] = __builtin_amdgcn_mfma_f32_16x16x32_bf16(
                        av[q][0], bv[fn][0], acc[2 * p + q][fn], 0, 0, 0);
                    acc[2 * p + q][fn] = __builtin_amdgcn_mfma_f32_16x16x32_bf16(
                        av[q][1], bv[fn][1], acc[2 * p + q][fn], 0, 0, 0);
                }
            PH_CLOSE();
        }
    }
#undef STAGE256
#undef PH_OPEN
#undef PH_CLOSE

#pragma unroll
    for (int fm = 0; fm < 8; ++fm) {
#pragma unroll
        for (int r = 0; r < 4; ++r) {
            const int gm = m0 + wm * 128 + fm * 16 + g4 * 4 + r;
#pragma unroll
            for (int fn = 0; fn < 4; ++fn) {
                const int gn = n0 + wn * 64 + fn * 16 + fr;
                const float v = acc[fm][fn][r];
                const long off = (long)z * sOz + (long)gm * ldc + gn;
                if (EPI == E_BF16) {
                    outb[off] = f2bf(v);
                } else {  // E_SMIX
                    const float pre = bf2f(aux1b[off]);
                    outb[off]  = f2bf(pre + 0.5f * __logf(v + 1e-6f));
                    outb2[off] = f2bf(v);
                }
            }
        }
    }
}

// ============================================================================
// 128x128-tile 2-phase GEMM (QKV / S / small matmuls).
// ============================================================================
template<int EPI>
__global__ __launch_bounds__(256) void gemm_nt(
    const u16* __restrict__ A, const u16* __restrict__ B,
    long sAz, long sBz, int lda, int ldb,
    int M, int Ncols, int K,
    float* __restrict__ outf, u16* __restrict__ outb,
    u16* __restrict__ outb2, u16* __restrict__ outb3,
    const float* __restrict__ aux1f, const u16* __restrict__ aux1b,
    const float* __restrict__ chainp,
    long sOz, int ldc, float scale, int zbase)
{
    __shared__ __align__(16) u16 As[2][BM * BK];
    __shared__ __align__(16) u16 Bs[2][BN * BK];

    const int z    = blockIdx.z;
    const u16* Ab  = A + (long)z * sAz;
    const u16* Bb  = B + (long)z * sBz;
    const int tid  = threadIdx.x;
    const int lane = tid & 63;
    const int wid  = tid >> 6;
    const int m0   = blockIdx.x * BM;
    const int n0   = blockIdx.y * BN;
    const int wr   = (wid >> 1) * 64;
    const int wc   = (wid & 1) * 64;

    f32x4 zero = {0.f, 0.f, 0.f, 0.f};
    f32x4 acc[4][4];
#pragma unroll
    for (int i = 0; i < 4; ++i)
#pragma unroll
        for (int j = 0; j < 4; ++j) acc[i][j] = zero;

    const int srow = tid >> 2;
    const int scol = (tid & 3) * 8;
    int bn0 = n0 + srow;      if (bn0 > Ncols - 1) bn0 = Ncols - 1;
    int bn1 = n0 + 64 + srow; if (bn1 > Ncols - 1) bn1 = Ncols - 1;
    const u16* gA0 = Ab + (long)(m0 + srow) * lda + scol;
    const u16* gA1 = Ab + (long)(m0 + 64 + srow) * lda + scol;
    const u16* gB0 = Bb + (long)bn0 * ldb + scol;
    const u16* gB1 = Bb + (long)bn1 * ldb + scol;

    const int kq = (lane >> 4) * 8;
    const int fr = lane & 15;

#define STAGE(buf, kk)                                  \
    do {                                                \
        g2lds16(gA0 + (kk), &As[buf][tid * 8]);         \
        g2lds16(gA1 + (kk), &As[buf][2048 + tid * 8]);  \
        g2lds16(gB0 + (kk), &Bs[buf][tid * 8]);         \
        g2lds16(gB1 + (kk), &Bs[buf][2048 + tid * 8]);  \
    } while (0)

    STAGE(0, 0);
    __syncthreads();
    int cur = 0;
    for (int k0 = 0; k0 < K; k0 += BK) {
        if (k0 + BK < K) STAGE(cur ^ 1, k0 + BK);
        s16x8 af[4], bfr[4];
#pragma unroll
        for (int i = 0; i < 4; ++i)
            af[i] = *(const s16x8*)(const void*)(&As[cur][(wr + i * 16 + fr) * BK + kq]);
#pragma unroll
        for (int j = 0; j < 4; ++j)
            bfr[j] = *(const s16x8*)(const void*)(&Bs[cur][(wc + j * 16 + fr) * BK + kq]);
#pragma unroll
        for (int i = 0; i < 4; ++i)
#pragma unroll
            for (int j = 0; j < 4; ++j)
                acc[i][j] = __builtin_amdgcn_mfma_f32_16x16x32_bf16(af[i], bfr[j], acc[i][j], 0, 0, 0);
        __syncthreads();
        cur ^= 1;
    }
#undef STAGE

    const int rbase = (lane >> 4) * 4;
    const int cidx  = lane & 15;
    float wgate = 0.f;
    if (EPI == E_Y) wgate = 1.f / (1.f + __expf(-chainp[0]));

#pragma unroll
    for (int i = 0; i < 4; ++i) {
#pragma unroll
        for (int r = 0; r < 4; ++r) {
            const int gm = m0 + wr + i * 16 + rbase + r;
#pragma unroll
            for (int j = 0; j < 4; ++j) {
                const int gn = n0 + wc + j * 16 + cidx;
                const float v = acc[i][j][r];
                if (EPI == E_F32) {
                    if (gn < Ncols) outf[(long)z * sOz + (long)gm * ldc + gn] = v * scale;
                } else if (EPI == E_BF16) {
                    if (gn < Ncols) outb[(long)z * sOz + (long)gm * ldc + gn] = f2bf(v * scale);
                } else if (EPI == E_QKV) {
                    const int b_ = gm >> 11, ntok = gm & 2047;
                    const int which = gn >> 9, h = (gn & 511) >> 6, d = gn & 63;
                    const long bh = (long)(b_ * 8 + h);
                    const u16 bv = f2bf(which == 0 ? v * scale : v);
                    if (which == 0)       outb [(bh * 2048 + ntok) * 64 + d] = bv;
                    else if (which == 1)  outb2[(bh * 2048 + ntok) * 64 + d] = bv;
                    else                  outb3[(bh * 64 + d) * 2048 + ntok] = bv;
                } else if (EPI == E_SMIX) {
                    const long off = (long)z * sOz + (long)gm * ldc + gn;
                    const float pre = bf2f(aux1b[off]);
                    outb[off]  = f2bf(pre + 0.5f * __logf(v + 1e-6f));
                    outb2[off] = f2bf(v);
                } else if (EPI == E_Y) {
                    if (gn < Ncols) {
                        const float yv = v + wgate * aux1f[(long)z * sOz + (long)gm * 64 + gn];
                        const int zg = zbase + z;
                        const int b_ = zg >> 3, h = zg & 7;
                        outb[((long)(b_ * 2048 + gm)) * 512 + h * 64 + gn] = f2bf(yv);
                    }
                }
            }
        }
    }
}

__global__ __launch_bounds__(256) void cvt_f32_bf16(const float* __restrict__ in,
                                                    u16* __restrict__ out, long n) {
    long i = (long)blockIdx.x * 256 + threadIdx.x;
    if (i < n) out[i] = f2bf(in[i]);
}

// in: [R][C] f32  ->  out: [C][R] bf16
__global__ __launch_bounds__(256) void cvt_transpose(const float* __restrict__ in,
                                                     u16* __restrict__ out, int R, int C) {
    long i = (long)blockIdx.x * 256 + threadIdx.x;
    if (i < (long)R * C) {
        int c = (int)(i / R), r = (int)(i % R);
        out[i] = f2bf(in[(long)r * C + c]);
    }
}

// per-z transpose of 2048x2048 bf16
__global__ __launch_bounds__(256) void trans2048(const u16* __restrict__ in,
                                                 u16* __restrict__ out) {
    __shared__ u16 tile[64][65];
    const long z = blockIdx.z;
    const u16* I = in + z * (long)2048 * 2048;
    u16* O       = out + z * (long)2048 * 2048;
    const int bx = blockIdx.x * 64, by = blockIdx.y * 64;
    const int t = threadIdx.x, c = t & 63, r4 = t >> 6;
#pragma unroll
    for (int s = 0; s < 16; ++s) {
        int r = s * 4 + r4;
        tile[r][c] = I[(long)(by + r) * 2048 + bx + c];
    }
    __syncthreads();
#pragma unroll
    for (int s = 0; s < 16; ++s) {
        int r = s * 4 + r4;
        O[(long)(bx + r) * 2048 + by + c] = tile[c][r];
    }
}

// One block per row (2048 bf16). MODE 0: A = softmax(S).
// MODE 1: A = softmax(S);  PreOut = 0.5*Spre + 0.75*S + 0.5*logaddexp(Spre,S)
template<int MODE>
__global__ __launch_bounds__(256) void row_softmax_bf(
    const u16* __restrict__ S, const u16* __restrict__ Spre,
    u16* __restrict__ A, u16* __restrict__ PreOut)
{
    const long row = blockIdx.x;
    const u16* p = S + row * 2048;
    const int t = threadIdx.x;
    s16x8 xv = *(const s16x8*)(const void*)(p + t * 8);
    float x[8];
#pragma unroll
    for (int e = 0; e < 8; ++e) x[e] = bf2f((u16)xv[e]);
    float m = x[0];
#pragma unroll
    for (int e = 1; e < 8; ++e) m = fmaxf(m, x[e]);
#pragma unroll
    for (int off = 32; off >= 1; off >>= 1) m = fmaxf(m, __shfl_xor(m, off));
    __shared__ float red[8];
    if ((t & 63) == 0) red[t >> 6] = m;
    __syncthreads();
    m = fmaxf(fmaxf(red[0], red[1]), fmaxf(red[2], red[3]));
    float s = 0.f, ee[8];
#pragma unroll
    for (int e = 0; e < 8; ++e) { ee[e] = __expf(x[e] - m); s += ee[e]; }
#pragma unroll
    for (int off = 32; off >= 1; off >>= 1) s += __shfl_xor(s, off);
    if ((t & 63) == 0) red[4 + (t >> 6)] = s;
    __syncthreads();
    s = red[4] + red[5] + red[6] + red[7];
    const float inv = 1.f / s;
    s16x8 o;
#pragma unroll
    for (int e = 0; e < 8; ++e) o[e] = (short)f2bf(ee[e] * inv);
    *(s16x8*)(void*)(A + row * 2048 + t * 8) = o;

    if (MODE == 1) {
        s16x8 pv = *(const s16x8*)(const void*)(Spre + row * 2048 + t * 8);
        s16x8 po;
#pragma unroll
        for (int e = 0; e < 8; ++e) {
            const float s1 = bf2f((u16)pv[e]);
            const float s2 = x[e];
            const float mx = fmaxf(s1, s2);
            const float lae = mx + log1pf(__expf(-fabsf(s1 - s2)));
            po[e] = (short)f2bf(0.5f * s1 + 0.75f * s2 + 0.5f * lae);
        }
        *(s16x8*)(void*)(PreOut + row * 2048 + t * 8) = po;
    }
}

extern "C" void kernel_launch(void* const* d_in, const int* in_sizes, int n_in,
                              void* d_out, int out_size, void* d_ws, size_t ws_size,
                              hipStream_t stream) {
    const float* x  = (const float*)d_in[0];
    const float* W1 = (const float*)d_in[1];
    const float* W2 = (const float*)d_in[2];
    const float* Wp = (const float*)d_in[3];
    const float* ch = (const float*)d_in[4];

    const int Bq = 2, N = 2048, D = 512, dk = 64, Z = 16;
    const long NN = (long)N * N;
    const long ND = (long)N * dk;
    (void)in_sizes; (void)n_in; (void)out_size;

    size_t ws_avail = ws_size ? ws_size : (size_t)-1;

    char* w = (char*)d_ws;
    size_t off = 0;
    auto alc = [&](size_t bytes) -> void* {
        void* p = w + off;
        off += (bytes + 255) & ~(size_t)255;
        return p;
    };

    // ---- persistent (~36 MiB) ----
    u16* xb   = (u16*)alc((long)Bq * N * D * 2);
    u16* W1t  = (u16*)alc((long)3 * D * D * 2);
    u16* W2t  = (u16*)alc((long)3 * D * D * 2);
    u16* Wpt  = (u16*)alc((long)D * D * 2);
    u16* Q1   = (u16*)alc(Z * ND * 2);
    u16* K1   = (u16*)alc(Z * ND * 2);
    u16* V1t  = (u16*)alc(Z * ND * 2);
    u16* Q2   = (u16*)alc(Z * ND * 2);
    u16* K2   = (u16*)alc(Z * ND * 2);
    u16* V2t  = (u16*)alc(Z * ND * 2);
    u16* y    = (u16*)alc((long)Bq * N * D * 2);
    const size_t persist = off;

    const size_t perz = 4 * (size_t)(NN * 2) + (size_t)(ND * 4) + 4096;
    int G = 16;
    while (G > 1 && persist + (size_t)G * perz + 65536 > ws_avail) G >>= 1;

    u16*  S1b = (u16*)alc((size_t)G * NN * 2);   // S1 -> Pre -> Smix
    u16*  S2b = (u16*)alc((size_t)G * NN * 2);   // S2 -> A2t
    u16*  A1b = (u16*)alc((size_t)G * NN * 2);   // A1 -> C2
    u16*  C1b = (u16*)alc((size_t)G * NN * 2);   // A2 -> C1 -> final A
    float* yc = (float*)alc((size_t)G * ND * 4);

    const dim3 blk(256);
    const float iscale = 0.125f;  // 1/sqrt(64)

    cvt_f32_bf16<<<(unsigned)(((long)Bq * N * D + 255) / 256), blk, 0, stream>>>(x, xb, (long)Bq * N * D);
    cvt_transpose<<<(3 * D * D + 255) / 256, blk, 0, stream>>>(W1, W1t, D, 3 * D);
    cvt_transpose<<<(3 * D * D + 255) / 256, blk, 0, stream>>>(W2, W2t, D, 3 * D);
    cvt_transpose<<<(D * D + 255) / 256, blk, 0, stream>>>(Wp, Wpt, D, D);

    gemm_nt<E_QKV><<<dim3(32, 12, 1), blk, 0, stream>>>(
        xb, W1t, 0L, 0L, D, D, Bq * N, 3 * D, D,
        nullptr, Q1, K1, V1t, nullptr, nullptr, nullptr, 0L, 0, iscale, 0);
    gemm_nt<E_QKV><<<dim3(32, 12, 1), blk, 0, stream>>>(
        xb, W2t, 0L, 0L, D, D, Bq * N, 3 * D, D,
        nullptr, Q2, K2, V2t, nullptr, nullptr, nullptr, 0L, 0, iscale, 0);

    for (int zb = 0; zb < Z; zb += G) {
        const u16* Q1z = Q1 + (long)zb * ND;
        const u16* K1z = K1 + (long)zb * ND;
        const u16* V1z = V1t + (long)zb * ND;
        const u16* Q2z = Q2 + (long)zb * ND;
        const u16* K2z = K2 + (long)zb * ND;
        const u16* V2z = V2t + (long)zb * ND;

        // S1 = Q1 K1^T (scale folded into Q) -> S1b ; S2 -> S2b  (bf16)
        gemm_nt<E_BF16><<<dim3(16, 16, G), blk, 0, stream>>>(
            Q1z, K1z, ND, ND, dk, dk, N, N, dk,
            nullptr, S1b, nullptr, nullptr, nullptr, nullptr, nullptr, NN, N, 1.f, 0);
        gemm_nt<E_BF16><<<dim3(16, 16, G), blk, 0, stream>>>(
            Q2z, K2z, ND, ND, dk, dk, N, N, dk,
            nullptr, S2b, nullptr, nullptr, nullptr, nullptr, nullptr, NN, N, 1.f, 0);

        // A1 = softmax(S1) -> A1b ; A2 = softmax(S2) -> C1b, Pre -> S1b (in-place)
        row_softmax_bf<0><<<G * N, blk, 0, stream>>>(S1b, nullptr, A1b, nullptr);
        row_softmax_bf<1><<<G * N, blk, 0, stream>>>(S2b, S1b, C1b, S1b);

        // A2t: C1b(A2) -> S2b
        trans2048<<<dim3(32, 32, G), blk, 0, stream>>>(C1b, S2b);

        // C1 = A1 @ A2 -> C1b
        gemm256_nt<E_BF16><<<dim3(8, 8, G), dim3(512), 0, stream>>>(
            A1b, S2b, NN, NN, N, N, N,
            C1b, nullptr, nullptr, NN, N);
        // C2 = C1 @ A2 ; Smix = Pre + 0.5*log(C2+eps) -> S1b ; C2 -> A1b
        gemm256_nt<E_SMIX><<<dim3(8, 8, G), dim3(512), 0, stream>>>(
            C1b, S2b, NN, NN, N, N, N,
            S1b, A1b, S1b, NN, N);
        // A = softmax(Smix) -> C1b
        row_softmax_bf<0><<<G * N, blk, 0, stream>>>(S1b, nullptr, C1b, nullptr);

        // y_chain = C2 @ v2  (f32 [z][N][64])
        gemm_nt<E_F32><<<dim3(16, 1, G), blk, 0, stream>>>(
            A1b, V2z, NN, ND, N, N, N, dk, N,
            yc, nullptr, nullptr, nullptr, nullptr, nullptr, nullptr, ND, dk, 1.f, 0);
        // y = A @ v1 + sigmoid(chain)*y_chain  -> bf16 [B,N,D]
        gemm_nt<E_Y><<<dim3(16, 1, G), blk, 0, stream>>>(
            C1b, V1z, NN, ND, N, N, N, dk, N,
            nullptr, y, nullptr, nullptr, yc, nullptr, ch, ND, dk, 1.f, zb);
    }

    // out = y @ Wproj   (f32)
    gemm_nt<E_F32><<<dim3(32, 4, 1), blk, 0, stream>>>(
        y, Wpt, 0L, 0L, D, D, Bq * N, D, D,
        (float*)d_out, nullptr, nullptr, nullptr, nullptr, nullptr, nullptr, 0L, D, 1.f, 0);
}

// Round 8
// 1213.512 us; speedup vs baseline: 1.5563x; 1.2855x over previous
//
#include <hip/hip_runtime.h>
#include <math.h>

typedef unsigned short u16;
typedef short s16x8 __attribute__((ext_vector_type(8)));
typedef float f32x4 __attribute__((ext_vector_type(4)));

#define BM 128
#define BN 128
#define BK 32

__device__ __forceinline__ u16 f2bf(float f) {
    union { float f; unsigned u; } v; v.f = f;
    unsigned u = v.u + 0x7FFFu + ((v.u >> 16) & 1u);
    return (u16)(u >> 16);
}
__device__ __forceinline__ float bf2f(u16 u) {
    union { unsigned u; float f; } v; v.u = ((unsigned)u) << 16; return v.f;
}

__device__ __forceinline__ void g2lds16(const void* g, void* l) {
    __builtin_amdgcn_global_load_lds(
        (const __attribute__((address_space(1))) void*)g,
        (__attribute__((address_space(3))) void*)l, 16, 0, 0);
}

enum { E_F32 = 0, E_BF16 = 1, E_QKV = 2, E_SMIX = 3 };

// ============================================================================
// 256x256-tile, BK=64, 8-wave counted-vmcnt pipelined GEMM (round-5 proven).
// ============================================================================
template<int EPI>
__global__ __launch_bounds__(512) void gemm256_nt(
    const u16* __restrict__ A, const u16* __restrict__ B,
    long sAz, long sBz, int lda, int ldb, int K,
    u16* __restrict__ outb, u16* __restrict__ outb2,
    const u16* __restrict__ aux1b, long sOz, int ldc)
{
    __shared__ __align__(16) u16 As[2][2][8192];
    __shared__ __align__(16) u16 Bs[2][2][8192];

    const int z   = blockIdx.z;
    const u16* Ab = A + (long)z * sAz;
    const u16* Bb = B + (long)z * sBz;
    const int t    = threadIdx.x;
    const int lane = t & 63;
    const int wid  = t >> 6;
    const int wm   = wid >> 2;
    const int wn   = wid & 3;
    const int fr   = lane & 15;
    const int g4   = lane >> 4;
    const int m0   = blockIdx.x * 256;
    const int n0   = blockIdx.y * 256;

    const int r0 = t >> 3;
    const int xc = ((t & 7) ^ (r0 & 7)) * 8;
    const u16* pA0 = Ab + (long)(m0 + r0) * lda + xc;
    const u16* pA1 = Ab + (long)(m0 + 64 + r0) * lda + xc;
    const u16* pA2 = Ab + (long)(m0 + 128 + r0) * lda + xc;
    const u16* pA3 = Ab + (long)(m0 + 192 + r0) * lda + xc;
    const u16* pB0 = Bb + (long)(n0 + r0) * ldb + xc;
    const u16* pB1 = Bb + (long)(n0 + 64 + r0) * ldb + xc;
    const u16* pB2 = Bb + (long)(n0 + 128 + r0) * ldb + xc;
    const u16* pB3 = Bb + (long)(n0 + 192 + r0) * ldb + xc;
    const int d0 = t * 8;
    const int d1 = t * 8 + 4096;

#define STAGE256(d, kk)                        \
    do {                                       \
        g2lds16(pA0 + (kk), &As[d][0][d0]);    \
        g2lds16(pA1 + (kk), &As[d][0][d1]);    \
        g2lds16(pA2 + (kk), &As[d][1][d0]);    \
        g2lds16(pA3 + (kk), &As[d][1][d1]);    \
        g2lds16(pB0 + (kk), &Bs[d][0][d0]);    \
        g2lds16(pB1 + (kk), &Bs[d][0][d1]);    \
        g2lds16(pB2 + (kk), &Bs[d][1][d0]);    \
        g2lds16(pB3 + (kk), &Bs[d][1][d1]);    \
    } while (0)

    const int swz  = fr & 7;
    const int rbS0 = fr * 64 + ((g4 ^ swz) * 8);
    const int rbS1 = fr * 64 + (((4 + g4) ^ swz) * 8);

    f32x4 acc[8][4];
#pragma unroll
    for (int i = 0; i < 8; ++i)
#pragma unroll
        for (int j = 0; j < 4; ++j) acc[i][j] = (f32x4){0.f, 0.f, 0.f, 0.f};

    STAGE256(0, 0);
    const int NT = K >> 6;
    for (int T = 0; T < NT; ++T) {
        const int d = T & 1;
        if (T + 1 < NT) {
            STAGE256(d ^ 1, (T + 1) << 6);
            asm volatile("s_waitcnt vmcnt(8)" ::: "memory");
        } else {
            asm volatile("s_waitcnt vmcnt(0)" ::: "memory");
        }
        __builtin_amdgcn_s_barrier();
        __builtin_amdgcn_sched_barrier(0);
        __builtin_amdgcn_s_setprio(1);
        {
            const u16* Abase = &As[d][wm][0];
            const u16* Bbase = &Bs[d][wn >> 1][(wn & 1) * 4096];
            s16x8 bv[4][2];
#pragma unroll
            for (int fn = 0; fn < 4; ++fn) {
                bv[fn][0] = *(const s16x8*)(const void*)(Bbase + fn * 1024 + rbS0);
                bv[fn][1] = *(const s16x8*)(const void*)(Bbase + fn * 1024 + rbS1);
            }
#pragma unroll
            for (int h = 0; h < 2; ++h) {
                s16x8 av[4][2];
#pragma unroll
                for (int fm = 0; fm < 4; ++fm) {
                    av[fm][0] = *(const s16x8*)(const void*)(Abase + (h * 4 + fm) * 1024 + rbS0);
                    av[fm][1] = *(const s16x8*)(const void*)(Abase + (h * 4 + fm) * 1024 + rbS1);
                }
#pragma unroll
                for (int fm = 0; fm < 4; ++fm)
#pragma unroll
                    for (int fn = 0; fn < 4; ++fn) {
                        acc[h * 4 + fm][fn] = __builtin_amdgcn_mfma_f32_16x16x32_bf16(
                            av[fm][0], bv[fn][0], acc[h * 4 + fm][fn], 0, 0, 0);
                        acc[h * 4 + fm][fn] = __builtin_amdgcn_mfma_f32_16x16x32_bf16(
                            av[fm][1], bv[fn][1], acc[h * 4 + fm][fn], 0, 0, 0);
                    }
            }
        }
        __builtin_amdgcn_s_setprio(0);
        __builtin_amdgcn_sched_barrier(0);
        __builtin_amdgcn_s_barrier();
    }
#undef STAGE256

#pragma unroll
    for (int fm = 0; fm < 8; ++fm) {
#pragma unroll
        for (int r = 0; r < 4; ++r) {
            const int gm = m0 + wm * 128 + fm * 16 + g4 * 4 + r;
#pragma unroll
            for (int fn = 0; fn < 4; ++fn) {
                const int gn = n0 + wn * 64 + fn * 16 + fr;
                const float v = acc[fm][fn][r];
                const long off = (long)z * sOz + (long)gm * ldc + gn;
                if (EPI == E_BF16) {
                    outb[off] = f2bf(v);
                } else {  // E_SMIX
                    const float pre = bf2f(aux1b[off]);
                    outb[off]  = f2bf(pre + 0.5f * __logf(v + 1e-6f));
                    outb2[off] = f2bf(v);
                }
            }
        }
    }
}

// ============================================================================
// Fused final: y = A@v1 + w*(C2@v2).  BM=64, BN=64(=dk), BK=64, 4 waves.
// Grid (32,1,G). Dual-stream staging, counted-vmcnt (same recipe as gemm256).
// ============================================================================
__global__ __launch_bounds__(256) void gemm_y(
    const u16* __restrict__ Amat,   // final attention A  [z][2048][2048]
    const u16* __restrict__ C2mat,  // C2                 [z][2048][2048]
    const u16* __restrict__ V1t,    // [z][64][2048]
    const u16* __restrict__ V2t,    // [z][64][2048]
    u16* __restrict__ yout,         // [B][2048][512]
    const float* __restrict__ chainp, int zbase)
{
    __shared__ __align__(16) u16 Aa[2][4096];
    __shared__ __align__(16) u16 Ac[2][4096];
    __shared__ __align__(16) u16 B1[2][4096];
    __shared__ __align__(16) u16 B2[2][4096];

    const long NNl = 2048L * 2048;
    const long NDl = 2048L * 64;
    const int z = blockIdx.z;
    const u16* Ab  = Amat  + z * NNl;
    const u16* Cb  = C2mat + z * NNl;
    const u16* V1b = V1t + z * NDl;
    const u16* V2b = V2t + z * NDl;

    const int t = threadIdx.x;
    const int lane = t & 63, wv = t >> 6;   // 4 waves
    const int fr = lane & 15, g4 = lane >> 4;
    const int m0 = blockIdx.x * 64;

    // staging: per tile 2 passes; pass p: row 32p + t>>3, granule t&7
    const int sr = t >> 3;
    const int sg = t & 7;
    const int c0 = (sg ^ (sr & 7)) * 8;         // pass 0 swizzled col
    const int c1 = (sg ^ ((sr + 32) & 7)) * 8;  // pass 1 (row+32)
    const u16* pAa0 = Ab  + (long)(m0 + sr) * 2048 + c0;
    const u16* pAa1 = Ab  + (long)(m0 + 32 + sr) * 2048 + c1;
    const u16* pAc0 = Cb  + (long)(m0 + sr) * 2048 + c0;
    const u16* pAc1 = Cb  + (long)(m0 + 32 + sr) * 2048 + c1;
    const u16* pB10 = V1b + (long)sr * 2048 + c0;
    const u16* pB11 = V1b + (long)(32 + sr) * 2048 + c1;
    const u16* pB20 = V2b + (long)sr * 2048 + c0;
    const u16* pB21 = V2b + (long)(32 + sr) * 2048 + c1;
    const int e0 = t * 8, e1 = t * 8 + 2048;

#define STAGEY(d, kk)                          \
    do {                                       \
        g2lds16(pAa0 + (kk), &Aa[d][e0]);      \
        g2lds16(pAa1 + (kk), &Aa[d][e1]);      \
        g2lds16(pAc0 + (kk), &Ac[d][e0]);      \
        g2lds16(pAc1 + (kk), &Ac[d][e1]);      \
        g2lds16(pB10 + (kk), &B1[d][e0]);      \
        g2lds16(pB11 + (kk), &B1[d][e1]);      \
        g2lds16(pB20 + (kk), &B2[d][e0]);      \
        g2lds16(pB21 + (kk), &B2[d][e1]);      \
    } while (0)

    const int swz  = fr & 7;
    const int rbS0 = fr * 64 + ((g4 ^ swz) * 8);
    const int rbS1 = fr * 64 + (((4 + g4) ^ swz) * 8);
    const int arow = wv * 16;   // wave's 16 output rows

    f32x4 acc1[4], acc2[4];
#pragma unroll
    for (int j = 0; j < 4; ++j) { acc1[j] = (f32x4){0,0,0,0}; acc2[j] = (f32x4){0,0,0,0}; }

    STAGEY(0, 0);
    for (int T = 0; T < 32; ++T) {
        const int d = T & 1;
        if (T + 1 < 32) {
            STAGEY(d ^ 1, (T + 1) << 6);
            asm volatile("s_waitcnt vmcnt(8)" ::: "memory");
        } else {
            asm volatile("s_waitcnt vmcnt(0)" ::: "memory");
        }
        __builtin_amdgcn_s_barrier();
        __builtin_amdgcn_sched_barrier(0);
        __builtin_amdgcn_s_setprio(1);
        {
            s16x8 a1[2], a2[2];
            a1[0] = *(const s16x8*)(const void*)(&Aa[d][arow * 64 + rbS0]);
            a1[1] = *(const s16x8*)(const void*)(&Aa[d][arow * 64 + rbS1]);
            a2[0] = *(const s16x8*)(const void*)(&Ac[d][arow * 64 + rbS0]);
            a2[1] = *(const s16x8*)(const void*)(&Ac[d][arow * 64 + rbS1]);
#pragma unroll
            for (int fn = 0; fn < 4; ++fn) {
                s16x8 b1a = *(const s16x8*)(const void*)(&B1[d][fn * 1024 + rbS0]);
                s16x8 b1b = *(const s16x8*)(const void*)(&B1[d][fn * 1024 + rbS1]);
                s16x8 b2a = *(const s16x8*)(const void*)(&B2[d][fn * 1024 + rbS0]);
                s16x8 b2b = *(const s16x8*)(const void*)(&B2[d][fn * 1024 + rbS1]);
                acc1[fn] = __builtin_amdgcn_mfma_f32_16x16x32_bf16(a1[0], b1a, acc1[fn], 0, 0, 0);
                acc1[fn] = __builtin_amdgcn_mfma_f32_16x16x32_bf16(a1[1], b1b, acc1[fn], 0, 0, 0);
                acc2[fn] = __builtin_amdgcn_mfma_f32_16x16x32_bf16(a2[0], b2a, acc2[fn], 0, 0, 0);
                acc2[fn] = __builtin_amdgcn_mfma_f32_16x16x32_bf16(a2[1], b2b, acc2[fn], 0, 0, 0);
            }
        }
        __builtin_amdgcn_s_setprio(0);
        __builtin_amdgcn_sched_barrier(0);
        __builtin_amdgcn_s_barrier();
    }
#undef STAGEY

    const float wgate = 1.f / (1.f + __expf(-chainp[0]));
    const int zg = zbase + z;
    const int b_ = zg >> 3, h = zg & 7;
#pragma unroll
    for (int r = 0; r < 4; ++r) {
        const int gm = m0 + arow + g4 * 4 + r;
#pragma unroll
        for (int fn = 0; fn < 4; ++fn) {
            const int gn = fn * 16 + fr;
            const float yv = acc1[fn][r] + wgate * acc2[fn][r];
            yout[((long)(b_ * 2048 + gm)) * 512 + h * 64 + gn] = f2bf(yv);
        }
    }
}

// ============================================================================
// 128x128-tile 2-phase GEMM (QKV / S / final proj).
// ============================================================================
template<int EPI>
__global__ __launch_bounds__(256) void gemm_nt(
    const u16* __restrict__ A, const u16* __restrict__ B,
    long sAz, long sBz, int lda, int ldb,
    int M, int Ncols, int K,
    float* __restrict__ outf, u16* __restrict__ outb,
    u16* __restrict__ outb2, u16* __restrict__ outb3,
    long sOz, int ldc, float scale)
{
    __shared__ __align__(16) u16 As[2][BM * BK];
    __shared__ __align__(16) u16 Bs[2][BN * BK];

    const int z    = blockIdx.z;
    const u16* Ab  = A + (long)z * sAz;
    const u16* Bb  = B + (long)z * sBz;
    const int tid  = threadIdx.x;
    const int lane = tid & 63;
    const int wid  = tid >> 6;
    const int m0   = blockIdx.x * BM;
    const int n0   = blockIdx.y * BN;
    const int wr   = (wid >> 1) * 64;
    const int wc   = (wid & 1) * 64;

    f32x4 zero = {0.f, 0.f, 0.f, 0.f};
    f32x4 acc[4][4];
#pragma unroll
    for (int i = 0; i < 4; ++i)
#pragma unroll
        for (int j = 0; j < 4; ++j) acc[i][j] = zero;

    const int srow = tid >> 2;
    const int scol = (tid & 3) * 8;
    int bn0 = n0 + srow;      if (bn0 > Ncols - 1) bn0 = Ncols - 1;
    int bn1 = n0 + 64 + srow; if (bn1 > Ncols - 1) bn1 = Ncols - 1;
    const u16* gA0 = Ab + (long)(m0 + srow) * lda + scol;
    const u16* gA1 = Ab + (long)(m0 + 64 + srow) * lda + scol;
    const u16* gB0 = Bb + (long)bn0 * ldb + scol;
    const u16* gB1 = Bb + (long)bn1 * ldb + scol;

    const int kq = (lane >> 4) * 8;
    const int fr = lane & 15;

#define STAGE(buf, kk)                                  \
    do {                                                \
        g2lds16(gA0 + (kk), &As[buf][tid * 8]);         \
        g2lds16(gA1 + (kk), &As[buf][2048 + tid * 8]);  \
        g2lds16(gB0 + (kk), &Bs[buf][tid * 8]);         \
        g2lds16(gB1 + (kk), &Bs[buf][2048 + tid * 8]);  \
    } while (0)

    STAGE(0, 0);
    __syncthreads();
    int cur = 0;
    for (int k0 = 0; k0 < K; k0 += BK) {
        if (k0 + BK < K) STAGE(cur ^ 1, k0 + BK);
        s16x8 af[4], bfr[4];
#pragma unroll
        for (int i = 0; i < 4; ++i)
            af[i] = *(const s16x8*)(const void*)(&As[cur][(wr + i * 16 + fr) * BK + kq]);
#pragma unroll
        for (int j = 0; j < 4; ++j)
            bfr[j] = *(const s16x8*)(const void*)(&Bs[cur][(wc + j * 16 + fr) * BK + kq]);
#pragma unroll
        for (int i = 0; i < 4; ++i)
#pragma unroll
            for (int j = 0; j < 4; ++j)
                acc[i][j] = __builtin_amdgcn_mfma_f32_16x16x32_bf16(af[i], bfr[j], acc[i][j], 0, 0, 0);
        __syncthreads();
        cur ^= 1;
    }
#undef STAGE

    const int rbase = (lane >> 4) * 4;
    const int cidx  = lane & 15;

#pragma unroll
    for (int i = 0; i < 4; ++i) {
#pragma unroll
        for (int r = 0; r < 4; ++r) {
            const int gm = m0 + wr + i * 16 + rbase + r;
#pragma unroll
            for (int j = 0; j < 4; ++j) {
                const int gn = n0 + wc + j * 16 + cidx;
                const float v = acc[i][j][r];
                if (EPI == E_F32) {
                    if (gn < Ncols) outf[(long)z * sOz + (long)gm * ldc + gn] = v * scale;
                } else if (EPI == E_BF16) {
                    if (gn < Ncols) outb[(long)z * sOz + (long)gm * ldc + gn] = f2bf(v * scale);
                } else if (EPI == E_QKV) {
                    const int b_ = gm >> 11, ntok = gm & 2047;
                    const int which = gn >> 9, h = (gn & 511) >> 6, d = gn & 63;
                    const long bh = (long)(b_ * 8 + h);
                    const u16 bv = f2bf(which == 0 ? v * scale : v);
                    if (which == 0)       outb [(bh * 2048 + ntok) * 64 + d] = bv;
                    else if (which == 1)  outb2[(bh * 2048 + ntok) * 64 + d] = bv;
                    else                  outb3[(bh * 64 + d) * 2048 + ntok] = bv;
                }
            }
        }
    }
}

__global__ __launch_bounds__(256) void cvt_f32_bf16(const float* __restrict__ in,
                                                    u16* __restrict__ out, long n) {
    long i = (long)blockIdx.x * 256 + threadIdx.x;
    if (i < n) out[i] = f2bf(in[i]);
}

__global__ __launch_bounds__(256) void cvt_transpose(const float* __restrict__ in,
                                                     u16* __restrict__ out, int R, int C) {
    long i = (long)blockIdx.x * 256 + threadIdx.x;
    if (i < (long)R * C) {
        int c = (int)(i / R), r = (int)(i % R);
        out[i] = f2bf(in[(long)r * C + c]);
    }
}

// per-z transpose of 2048x2048 bf16
__global__ __launch_bounds__(256) void trans2048(const u16* __restrict__ in,
                                                 u16* __restrict__ out) {
    __shared__ u16 tile[64][65];
    const long z = blockIdx.z;
    const u16* I = in + z * (long)2048 * 2048;
    u16* O       = out + z * (long)2048 * 2048;
    const int bx = blockIdx.x * 64, by = blockIdx.y * 64;
    const int t = threadIdx.x, c = t & 63, r4 = t >> 6;
#pragma unroll
    for (int s = 0; s < 16; ++s) {
        int r = s * 4 + r4;
        tile[r][c] = I[(long)(by + r) * 2048 + bx + c];
    }
    __syncthreads();
#pragma unroll
    for (int s = 0; s < 16; ++s) {
        int r = s * 4 + r4;
        O[(long)(bx + r) * 2048 + by + c] = tile[c][r];
    }
}

// Fused dual softmax: A1 = softmax(S1); A2 = softmax(S2);
// Pre = 0.5*S1 + 0.75*S2 + 0.5*logaddexp(S1,S2)  (Pre may alias S1).
__global__ __launch_bounds__(256) void sm01(
    const u16* __restrict__ S1, const u16* __restrict__ S2,
    u16* __restrict__ A1, u16* __restrict__ A2, u16* __restrict__ Pre)
{
    const long row = blockIdx.x;
    const int t = threadIdx.x;
    s16x8 v1 = *(const s16x8*)(const void*)(S1 + row * 2048 + t * 8);
    s16x8 v2 = *(const s16x8*)(const void*)(S2 + row * 2048 + t * 8);
    float x1[8], x2[8];
#pragma unroll
    for (int e = 0; e < 8; ++e) { x1[e] = bf2f((u16)v1[e]); x2[e] = bf2f((u16)v2[e]); }
    float m1 = x1[0], m2 = x2[0];
#pragma unroll
    for (int e = 1; e < 8; ++e) { m1 = fmaxf(m1, x1[e]); m2 = fmaxf(m2, x2[e]); }
#pragma unroll
    for (int off = 32; off >= 1; off >>= 1) {
        m1 = fmaxf(m1, __shfl_xor(m1, off));
        m2 = fmaxf(m2, __shfl_xor(m2, off));
    }
    __shared__ float red[16];
    if ((t & 63) == 0) { red[t >> 6] = m1; red[4 + (t >> 6)] = m2; }
    __syncthreads();
    m1 = fmaxf(fmaxf(red[0], red[1]), fmaxf(red[2], red[3]));
    m2 = fmaxf(fmaxf(red[4], red[5]), fmaxf(red[6], red[7]));
    float s1 = 0.f, s2 = 0.f, e1[8], e2[8];
#pragma unroll
    for (int e = 0; e < 8; ++e) {
        e1[e] = __expf(x1[e] - m1); s1 += e1[e];
        e2[e] = __expf(x2[e] - m2); s2 += e2[e];
    }
#pragma unroll
    for (int off = 32; off >= 1; off >>= 1) {
        s1 += __shfl_xor(s1, off);
        s2 += __shfl_xor(s2, off);
    }
    if ((t & 63) == 0) { red[8 + (t >> 6)] = s1; red[12 + (t >> 6)] = s2; }
    __syncthreads();
    s1 = red[8] + red[9] + red[10] + red[11];
    s2 = red[12] + red[13] + red[14] + red[15];
    const float i1 = 1.f / s1, i2 = 1.f / s2;
    s16x8 o1, o2, op;
#pragma unroll
    for (int e = 0; e < 8; ++e) {
        o1[e] = (short)f2bf(e1[e] * i1);
        o2[e] = (short)f2bf(e2[e] * i2);
        const float a = x1[e], b = x2[e];
        const float lae = fmaxf(a, b) + log1pf(__expf(-fabsf(a - b)));
        op[e] = (short)f2bf(0.5f * a + 0.75f * b + 0.5f * lae);
    }
    *(s16x8*)(void*)(A1  + row * 2048 + t * 8) = o1;
    *(s16x8*)(void*)(A2  + row * 2048 + t * 8) = o2;
    *(s16x8*)(void*)(Pre + row * 2048 + t * 8) = op;
}

// One block per row: A = softmax(S)  (final mix softmax)
__global__ __launch_bounds__(256) void row_softmax_bf(
    const u16* __restrict__ S, u16* __restrict__ A)
{
    const long row = blockIdx.x;
    const int t = threadIdx.x;
    s16x8 xv = *(const s16x8*)(const void*)(S + row * 2048 + t * 8);
    float x[8];
#pragma unroll
    for (int e = 0; e < 8; ++e) x[e] = bf2f((u16)xv[e]);
    float m = x[0];
#pragma unroll
    for (int e = 1; e < 8; ++e) m = fmaxf(m, x[e]);
#pragma unroll
    for (int off = 32; off >= 1; off >>= 1) m = fmaxf(m, __shfl_xor(m, off));
    __shared__ float red[8];
    if ((t & 63) == 0) red[t >> 6] = m;
    __syncthreads();
    m = fmaxf(fmaxf(red[0], red[1]), fmaxf(red[2], red[3]));
    float s = 0.f, ee[8];
#pragma unroll
    for (int e = 0; e < 8; ++e) { ee[e] = __expf(x[e] - m); s += ee[e]; }
#pragma unroll
    for (int off = 32; off >= 1; off >>= 1) s += __shfl_xor(s, off);
    if ((t & 63) == 0) red[4 + (t >> 6)] = s;
    __syncthreads();
    s = red[4] + red[5] + red[6] + red[7];
    const float inv = 1.f / s;
    s16x8 o;
#pragma unroll
    for (int e = 0; e < 8; ++e) o[e] = (short)f2bf(ee[e] * inv);
    *(s16x8*)(void*)(A + row * 2048 + t * 8) = o;
}

extern "C" void kernel_launch(void* const* d_in, const int* in_sizes, int n_in,
                              void* d_out, int out_size, void* d_ws, size_t ws_size,
                              hipStream_t stream) {
    const float* x  = (const float*)d_in[0];
    const float* W1 = (const float*)d_in[1];
    const float* W2 = (const float*)d_in[2];
    const float* Wp = (const float*)d_in[3];
    const float* ch = (const float*)d_in[4];

    const int Bq = 2, N = 2048, D = 512, dk = 64, Z = 16;
    const long NN = (long)N * N;
    const long ND = (long)N * dk;
    (void)in_sizes; (void)n_in; (void)out_size;

    size_t ws_avail = ws_size ? ws_size : (size_t)-1;

    char* w = (char*)d_ws;
    size_t off = 0;
    auto alc = [&](size_t bytes) -> void* {
        void* p = w + off;
        off += (bytes + 255) & ~(size_t)255;
        return p;
    };

    // ---- persistent (~36 MiB) ----
    u16* xb   = (u16*)alc((long)Bq * N * D * 2);
    u16* W1t  = (u16*)alc((long)3 * D * D * 2);
    u16* W2t  = (u16*)alc((long)3 * D * D * 2);
    u16* Wpt  = (u16*)alc((long)D * D * 2);
    u16* Q1   = (u16*)alc(Z * ND * 2);
    u16* K1   = (u16*)alc(Z * ND * 2);
    u16* V1t  = (u16*)alc(Z * ND * 2);
    u16* Q2   = (u16*)alc(Z * ND * 2);
    u16* K2   = (u16*)alc(Z * ND * 2);
    u16* V2t  = (u16*)alc(Z * ND * 2);
    u16* y    = (u16*)alc((long)Bq * N * D * 2);
    const size_t persist = off;

    const size_t perz = 4 * (size_t)(NN * 2) + 4096;
    int G = 16;
    while (G > 1 && persist + (size_t)G * perz + 65536 > ws_avail) G >>= 1;

    u16*  S1b = (u16*)alc((size_t)G * NN * 2);   // S1 -> Pre -> Smix
    u16*  S2b = (u16*)alc((size_t)G * NN * 2);   // S2 -> A2t
    u16*  A1b = (u16*)alc((size_t)G * NN * 2);   // A1 -> C2
    u16*  C1b = (u16*)alc((size_t)G * NN * 2);   // A2 -> C1 -> final A

    const dim3 blk(256);
    const float iscale = 0.125f;  // 1/sqrt(64)

    cvt_f32_bf16<<<(unsigned)(((long)Bq * N * D + 255) / 256), blk, 0, stream>>>(x, xb, (long)Bq * N * D);
    cvt_transpose<<<(3 * D * D + 255) / 256, blk, 0, stream>>>(W1, W1t, D, 3 * D);
    cvt_transpose<<<(3 * D * D + 255) / 256, blk, 0, stream>>>(W2, W2t, D, 3 * D);
    cvt_transpose<<<(D * D + 255) / 256, blk, 0, stream>>>(Wp, Wpt, D, D);

    gemm_nt<E_QKV><<<dim3(32, 12, 1), blk, 0, stream>>>(
        xb, W1t, 0L, 0L, D, D, Bq * N, 3 * D, D,
        nullptr, Q1, K1, V1t, 0L, 0, iscale);
    gemm_nt<E_QKV><<<dim3(32, 12, 1), blk, 0, stream>>>(
        xb, W2t, 0L, 0L, D, D, Bq * N, 3 * D, D,
        nullptr, Q2, K2, V2t, 0L, 0, iscale);

    for (int zb = 0; zb < Z; zb += G) {
        const u16* Q1z = Q1 + (long)zb * ND;
        const u16* K1z = K1 + (long)zb * ND;
        const u16* V1z = V1t + (long)zb * ND;
        const u16* Q2z = Q2 + (long)zb * ND;
        const u16* K2z = K2 + (long)zb * ND;
        const u16* V2z = V2t + (long)zb * ND;

        // S1 -> S1b ; S2 -> S2b  (bf16, scale folded into Q)
        gemm_nt<E_BF16><<<dim3(16, 16, G), blk, 0, stream>>>(
            Q1z, K1z, ND, ND, dk, dk, N, N, dk,
            nullptr, S1b, nullptr, nullptr, NN, N, 1.f);
        gemm_nt<E_BF16><<<dim3(16, 16, G), blk, 0, stream>>>(
            Q2z, K2z, ND, ND, dk, dk, N, N, dk,
            nullptr, S2b, nullptr, nullptr, NN, N, 1.f);

        // fused dual softmax: A1 -> A1b ; A2 -> C1b ; Pre -> S1b (in-place)
        sm01<<<G * N, blk, 0, stream>>>(S1b, S2b, A1b, C1b, S1b);

        // A2t: C1b(A2) -> S2b
        trans2048<<<dim3(32, 32, G), blk, 0, stream>>>(C1b, S2b);

        // C1 = A1 @ A2 -> C1b
        gemm256_nt<E_BF16><<<dim3(8, 8, G), dim3(512), 0, stream>>>(
            A1b, S2b, NN, NN, N, N, N,
            C1b, nullptr, nullptr, NN, N);
        // C2 = C1 @ A2 ; Smix = Pre + 0.5*log(C2+eps) -> S1b ; C2 -> A1b
        gemm256_nt<E_SMIX><<<dim3(8, 8, G), dim3(512), 0, stream>>>(
            C1b, S2b, NN, NN, N, N, N,
            S1b, A1b, S1b, NN, N);
        // A = softmax(Smix) -> C1b
        row_softmax_bf<<<G * N, blk, 0, stream>>>(S1b, C1b);

        // y = A@v1 + sigmoid(chain)*(C2@v2)  -> bf16 [B,N,D]
        gemm_y<<<dim3(32, 1, G), blk, 0, stream>>>(
            C1b, A1b, V1z, V2z, y, ch, zb);
    }

    // out = y @ Wproj   (f32)
    gemm_nt<E_F32><<<dim3(32, 4, 1), blk, 0, stream>>>(
        y, Wpt, 0L, 0L, D, D, Bq * N, D, D,
        (float*)d_out, nullptr, nullptr, nullptr, 0L, D, 1.f);
}

// Round 9
// 1209.694 us; speedup vs baseline: 1.5612x; 1.0032x over previous
//
#include <hip/hip_runtime.h>
#include <math.h>

typedef unsigned short u16;
typedef short s16x8 __attribute__((ext_vector_type(8)));
typedef float f32x4 __attribute__((ext_vector_type(4)));

#define BM 128
#define BN 128
#define BK 32

__device__ __forceinline__ u16 f2bf(float f) {
    union { float f; unsigned u; } v; v.f = f;
    unsigned u = v.u + 0x7FFFu + ((v.u >> 16) & 1u);
    return (u16)(u >> 16);
}
__device__ __forceinline__ float bf2f(u16 u) {
    union { unsigned u; float f; } v; v.u = ((unsigned)u) << 16; return v.f;
}

__device__ __forceinline__ void g2lds16(const void* g, void* l) {
    __builtin_amdgcn_global_load_lds(
        (const __attribute__((address_space(1))) void*)g,
        (__attribute__((address_space(3))) void*)l, 16, 0, 0);
}

enum { E_F32 = 0, E_BF16 = 1, E_QKV = 2, E_SMIX = 3 };

// ============================================================================
// 256x256-tile, BK=64, 8-wave counted-vmcnt pipelined GEMM (round-5 proven).
// ============================================================================
template<int EPI>
__global__ __launch_bounds__(512) void gemm256_nt(
    const u16* __restrict__ A, const u16* __restrict__ B,
    long sAz, long sBz, int lda, int ldb, int K,
    u16* __restrict__ outb, u16* __restrict__ outb2,
    const u16* __restrict__ aux1b, long sOz, int ldc)
{
    __shared__ __align__(16) u16 As[2][2][8192];
    __shared__ __align__(16) u16 Bs[2][2][8192];

    const int z   = blockIdx.z;
    const u16* Ab = A + (long)z * sAz;
    const u16* Bb = B + (long)z * sBz;
    const int t    = threadIdx.x;
    const int lane = t & 63;
    const int wid  = t >> 6;
    const int wm   = wid >> 2;
    const int wn   = wid & 3;
    const int fr   = lane & 15;
    const int g4   = lane >> 4;
    const int m0   = blockIdx.x * 256;
    const int n0   = blockIdx.y * 256;

    const int r0 = t >> 3;
    const int xc = ((t & 7) ^ (r0 & 7)) * 8;
    const u16* pA0 = Ab + (long)(m0 + r0) * lda + xc;
    const u16* pA1 = Ab + (long)(m0 + 64 + r0) * lda + xc;
    const u16* pA2 = Ab + (long)(m0 + 128 + r0) * lda + xc;
    const u16* pA3 = Ab + (long)(m0 + 192 + r0) * lda + xc;
    const u16* pB0 = Bb + (long)(n0 + r0) * ldb + xc;
    const u16* pB1 = Bb + (long)(n0 + 64 + r0) * ldb + xc;
    const u16* pB2 = Bb + (long)(n0 + 128 + r0) * ldb + xc;
    const u16* pB3 = Bb + (long)(n0 + 192 + r0) * ldb + xc;
    const int d0 = t * 8;
    const int d1 = t * 8 + 4096;

#define STAGE256(d, kk)                        \
    do {                                       \
        g2lds16(pA0 + (kk), &As[d][0][d0]);    \
        g2lds16(pA1 + (kk), &As[d][0][d1]);    \
        g2lds16(pA2 + (kk), &As[d][1][d0]);    \
        g2lds16(pA3 + (kk), &As[d][1][d1]);    \
        g2lds16(pB0 + (kk), &Bs[d][0][d0]);    \
        g2lds16(pB1 + (kk), &Bs[d][0][d1]);    \
        g2lds16(pB2 + (kk), &Bs[d][1][d0]);    \
        g2lds16(pB3 + (kk), &Bs[d][1][d1]);    \
    } while (0)

    const int swz  = fr & 7;
    const int rbS0 = fr * 64 + ((g4 ^ swz) * 8);
    const int rbS1 = fr * 64 + (((4 + g4) ^ swz) * 8);

    f32x4 acc[8][4];
#pragma unroll
    for (int i = 0; i < 8; ++i)
#pragma unroll
        for (int j = 0; j < 4; ++j) acc[i][j] = (f32x4){0.f, 0.f, 0.f, 0.f};

    STAGE256(0, 0);
    const int NT = K >> 6;
    for (int T = 0; T < NT; ++T) {
        const int d = T & 1;
        if (T + 1 < NT) {
            STAGE256(d ^ 1, (T + 1) << 6);
            asm volatile("s_waitcnt vmcnt(8)" ::: "memory");
        } else {
            asm volatile("s_waitcnt vmcnt(0)" ::: "memory");
        }
        __builtin_amdgcn_s_barrier();
        __builtin_amdgcn_sched_barrier(0);
        __builtin_amdgcn_s_setprio(1);
        {
            const u16* Abase = &As[d][wm][0];
            const u16* Bbase = &Bs[d][wn >> 1][(wn & 1) * 4096];
            s16x8 bv[4][2];
#pragma unroll
            for (int fn = 0; fn < 4; ++fn) {
                bv[fn][0] = *(const s16x8*)(const void*)(Bbase + fn * 1024 + rbS0);
                bv[fn][1] = *(const s16x8*)(const void*)(Bbase + fn * 1024 + rbS1);
            }
#pragma unroll
            for (int h = 0; h < 2; ++h) {
                s16x8 av[4][2];
#pragma unroll
                for (int fm = 0; fm < 4; ++fm) {
                    av[fm][0] = *(const s16x8*)(const void*)(Abase + (h * 4 + fm) * 1024 + rbS0);
                    av[fm][1] = *(const s16x8*)(const void*)(Abase + (h * 4 + fm) * 1024 + rbS1);
                }
#pragma unroll
                for (int fm = 0; fm < 4; ++fm)
#pragma unroll
                    for (int fn = 0; fn < 4; ++fn) {
                        acc[h * 4 + fm][fn] = __builtin_amdgcn_mfma_f32_16x16x32_bf16(
                            av[fm][0], bv[fn][0], acc[h * 4 + fm][fn], 0, 0, 0);
                        acc[h * 4 + fm][fn] = __builtin_amdgcn_mfma_f32_16x16x32_bf16(
                            av[fm][1], bv[fn][1], acc[h * 4 + fm][fn], 0, 0, 0);
                    }
            }
        }
        __builtin_amdgcn_s_setprio(0);
        __builtin_amdgcn_sched_barrier(0);
        __builtin_amdgcn_s_barrier();
    }
#undef STAGE256

#pragma unroll
    for (int fm = 0; fm < 8; ++fm) {
#pragma unroll
        for (int r = 0; r < 4; ++r) {
            const int gm = m0 + wm * 128 + fm * 16 + g4 * 4 + r;
#pragma unroll
            for (int fn = 0; fn < 4; ++fn) {
                const int gn = n0 + wn * 64 + fn * 16 + fr;
                const float v = acc[fm][fn][r];
                const long off = (long)z * sOz + (long)gm * ldc + gn;
                if (EPI == E_BF16) {
                    outb[off] = f2bf(v);
                } else {  // E_SMIX
                    const float pre = bf2f(aux1b[off]);
                    outb[off]  = f2bf(pre + 0.5f * __logf(v + 1e-6f));
                    outb2[off] = f2bf(v);
                }
            }
        }
    }
}

// ============================================================================
// Fused final: y = A@v1 + w*(C2@v2).  BM=64, BN=64(=dk), BK=64, 4 waves.
// ============================================================================
__global__ __launch_bounds__(256) void gemm_y(
    const u16* __restrict__ Amat,   // final attention A  [z][2048][2048]
    const u16* __restrict__ C2mat,  // C2                 [z][2048][2048]
    const u16* __restrict__ V1t,    // [z][64][2048]
    const u16* __restrict__ V2t,    // [z][64][2048]
    u16* __restrict__ yout,         // [B][2048][512]
    const float* __restrict__ chainp, int zbase)
{
    __shared__ __align__(16) u16 Aa[2][4096];
    __shared__ __align__(16) u16 Ac[2][4096];
    __shared__ __align__(16) u16 B1[2][4096];
    __shared__ __align__(16) u16 B2[2][4096];

    const long NNl = 2048L * 2048;
    const long NDl = 2048L * 64;
    const int z = blockIdx.z;
    const u16* Ab  = Amat  + z * NNl;
    const u16* Cb  = C2mat + z * NNl;
    const u16* V1b = V1t + z * NDl;
    const u16* V2b = V2t + z * NDl;

    const int t = threadIdx.x;
    const int lane = t & 63, wv = t >> 6;   // 4 waves
    const int fr = lane & 15, g4 = lane >> 4;
    const int m0 = blockIdx.x * 64;

    const int sr = t >> 3;
    const int sg = t & 7;
    const int c0 = (sg ^ (sr & 7)) * 8;
    const int c1 = (sg ^ ((sr + 32) & 7)) * 8;
    const u16* pAa0 = Ab  + (long)(m0 + sr) * 2048 + c0;
    const u16* pAa1 = Ab  + (long)(m0 + 32 + sr) * 2048 + c1;
    const u16* pAc0 = Cb  + (long)(m0 + sr) * 2048 + c0;
    const u16* pAc1 = Cb  + (long)(m0 + 32 + sr) * 2048 + c1;
    const u16* pB10 = V1b + (long)sr * 2048 + c0;
    const u16* pB11 = V1b + (long)(32 + sr) * 2048 + c1;
    const u16* pB20 = V2b + (long)sr * 2048 + c0;
    const u16* pB21 = V2b + (long)(32 + sr) * 2048 + c1;
    const int e0 = t * 8, e1 = t * 8 + 2048;

#define STAGEY(d, kk)                          \
    do {                                       \
        g2lds16(pAa0 + (kk), &Aa[d][e0]);      \
        g2lds16(pAa1 + (kk), &Aa[d][e1]);      \
        g2lds16(pAc0 + (kk), &Ac[d][e0]);      \
        g2lds16(pAc1 + (kk), &Ac[d][e1]);      \
        g2lds16(pB10 + (kk), &B1[d][e0]);      \
        g2lds16(pB11 + (kk), &B1[d][e1]);      \
        g2lds16(pB20 + (kk), &B2[d][e0]);      \
        g2lds16(pB21 + (kk), &B2[d][e1]);      \
    } while (0)

    const int swz  = fr & 7;
    const int rbS0 = fr * 64 + ((g4 ^ swz) * 8);
    const int rbS1 = fr * 64 + (((4 + g4) ^ swz) * 8);
    const int arow = wv * 16;

    f32x4 acc1[4], acc2[4];
#pragma unroll
    for (int j = 0; j < 4; ++j) { acc1[j] = (f32x4){0,0,0,0}; acc2[j] = (f32x4){0,0,0,0}; }

    STAGEY(0, 0);
    for (int T = 0; T < 32; ++T) {
        const int d = T & 1;
        if (T + 1 < 32) {
            STAGEY(d ^ 1, (T + 1) << 6);
            asm volatile("s_waitcnt vmcnt(8)" ::: "memory");
        } else {
            asm volatile("s_waitcnt vmcnt(0)" ::: "memory");
        }
        __builtin_amdgcn_s_barrier();
        __builtin_amdgcn_sched_barrier(0);
        __builtin_amdgcn_s_setprio(1);
        {
            s16x8 a1[2], a2[2];
            a1[0] = *(const s16x8*)(const void*)(&Aa[d][arow * 64 + rbS0]);
            a1[1] = *(const s16x8*)(const void*)(&Aa[d][arow * 64 + rbS1]);
            a2[0] = *(const s16x8*)(const void*)(&Ac[d][arow * 64 + rbS0]);
            a2[1] = *(const s16x8*)(const void*)(&Ac[d][arow * 64 + rbS1]);
#pragma unroll
            for (int fn = 0; fn < 4; ++fn) {
                s16x8 b1a = *(const s16x8*)(const void*)(&B1[d][fn * 1024 + rbS0]);
                s16x8 b1b = *(const s16x8*)(const void*)(&B1[d][fn * 1024 + rbS1]);
                s16x8 b2a = *(const s16x8*)(const void*)(&B2[d][fn * 1024 + rbS0]);
                s16x8 b2b = *(const s16x8*)(const void*)(&B2[d][fn * 1024 + rbS1]);
                acc1[fn] = __builtin_amdgcn_mfma_f32_16x16x32_bf16(a1[0], b1a, acc1[fn], 0, 0, 0);
                acc1[fn] = __builtin_amdgcn_mfma_f32_16x16x32_bf16(a1[1], b1b, acc1[fn], 0, 0, 0);
                acc2[fn] = __builtin_amdgcn_mfma_f32_16x16x32_bf16(a2[0], b2a, acc2[fn], 0, 0, 0);
                acc2[fn] = __builtin_amdgcn_mfma_f32_16x16x32_bf16(a2[1], b2b, acc2[fn], 0, 0, 0);
            }
        }
        __builtin_amdgcn_s_setprio(0);
        __builtin_amdgcn_sched_barrier(0);
        __builtin_amdgcn_s_barrier();
    }
#undef STAGEY

    const float wgate = 1.f / (1.f + __expf(-chainp[0]));
    const int zg = zbase + z;
    const int b_ = zg >> 3, h = zg & 7;
#pragma unroll
    for (int r = 0; r < 4; ++r) {
        const int gm = m0 + arow + g4 * 4 + r;
#pragma unroll
        for (int fn = 0; fn < 4; ++fn) {
            const int gn = fn * 16 + fr;
            const float yv = acc1[fn][r] + wgate * acc2[fn][r];
            yout[((long)(b_ * 2048 + gm)) * 512 + h * 64 + gn] = f2bf(yv);
        }
    }
}

// ============================================================================
// 128x128-tile 2-phase GEMM (QKV / S / final proj).
// ============================================================================
template<int EPI>
__global__ __launch_bounds__(256) void gemm_nt(
    const u16* __restrict__ A, const u16* __restrict__ B,
    long sAz, long sBz, int lda, int ldb,
    int M, int Ncols, int K,
    float* __restrict__ outf, u16* __restrict__ outb,
    u16* __restrict__ outb2, u16* __restrict__ outb3,
    long sOz, int ldc, float scale)
{
    __shared__ __align__(16) u16 As[2][BM * BK];
    __shared__ __align__(16) u16 Bs[2][BN * BK];

    const int z    = blockIdx.z;
    const u16* Ab  = A + (long)z * sAz;
    const u16* Bb  = B + (long)z * sBz;
    const int tid  = threadIdx.x;
    const int lane = tid & 63;
    const int wid  = tid >> 6;
    const int m0   = blockIdx.x * BM;
    const int n0   = blockIdx.y * BN;
    const int wr   = (wid >> 1) * 64;
    const int wc   = (wid & 1) * 64;

    f32x4 zero = {0.f, 0.f, 0.f, 0.f};
    f32x4 acc[4][4];
#pragma unroll
    for (int i = 0; i < 4; ++i)
#pragma unroll
        for (int j = 0; j < 4; ++j) acc[i][j] = zero;

    const int srow = tid >> 2;
    const int scol = (tid & 3) * 8;
    int bn0 = n0 + srow;      if (bn0 > Ncols - 1) bn0 = Ncols - 1;
    int bn1 = n0 + 64 + srow; if (bn1 > Ncols - 1) bn1 = Ncols - 1;
    const u16* gA0 = Ab + (long)(m0 + srow) * lda + scol;
    const u16* gA1 = Ab + (long)(m0 + 64 + srow) * lda + scol;
    const u16* gB0 = Bb + (long)bn0 * ldb + scol;
    const u16* gB1 = Bb + (long)bn1 * ldb + scol;

    const int kq = (lane >> 4) * 8;
    const int fr = lane & 15;

#define STAGE(buf, kk)                                  \
    do {                                                \
        g2lds16(gA0 + (kk), &As[buf][tid * 8]);         \
        g2lds16(gA1 + (kk), &As[buf][2048 + tid * 8]);  \
        g2lds16(gB0 + (kk), &Bs[buf][tid * 8]);         \
        g2lds16(gB1 + (kk), &Bs[buf][2048 + tid * 8]);  \
    } while (0)

    STAGE(0, 0);
    __syncthreads();
    int cur = 0;
    for (int k0 = 0; k0 < K; k0 += BK) {
        if (k0 + BK < K) STAGE(cur ^ 1, k0 + BK);
        s16x8 af[4], bfr[4];
#pragma unroll
        for (int i = 0; i < 4; ++i)
            af[i] = *(const s16x8*)(const void*)(&As[cur][(wr + i * 16 + fr) * BK + kq]);
#pragma unroll
        for (int j = 0; j < 4; ++j)
            bfr[j] = *(const s16x8*)(const void*)(&Bs[cur][(wc + j * 16 + fr) * BK + kq]);
#pragma unroll
        for (int i = 0; i < 4; ++i)
#pragma unroll
            for (int j = 0; j < 4; ++j)
                acc[i][j] = __builtin_amdgcn_mfma_f32_16x16x32_bf16(af[i], bfr[j], acc[i][j], 0, 0, 0);
        __syncthreads();
        cur ^= 1;
    }
#undef STAGE

    const int rbase = (lane >> 4) * 4;
    const int cidx  = lane & 15;

#pragma unroll
    for (int i = 0; i < 4; ++i) {
#pragma unroll
        for (int r = 0; r < 4; ++r) {
            const int gm = m0 + wr + i * 16 + rbase + r;
#pragma unroll
            for (int j = 0; j < 4; ++j) {
                const int gn = n0 + wc + j * 16 + cidx;
                const float v = acc[i][j][r];
                if (EPI == E_F32) {
                    if (gn < Ncols) outf[(long)z * sOz + (long)gm * ldc + gn] = v * scale;
                } else if (EPI == E_BF16) {
                    if (gn < Ncols) outb[(long)z * sOz + (long)gm * ldc + gn] = f2bf(v * scale);
                } else if (EPI == E_QKV) {
                    const int b_ = gm >> 11, ntok = gm & 2047;
                    const int which = gn >> 9, h = (gn & 511) >> 6, d = gn & 63;
                    const long bh = (long)(b_ * 8 + h);
                    const u16 bv = f2bf(which == 0 ? v * scale : v);
                    if (which == 0)       outb [(bh * 2048 + ntok) * 64 + d] = bv;
                    else if (which == 1)  outb2[(bh * 2048 + ntok) * 64 + d] = bv;
                    else                  outb3[(bh * 64 + d) * 2048 + ntok] = bv;
                }
            }
        }
    }
}

__global__ __launch_bounds__(256) void cvt_f32_bf16(const float* __restrict__ in,
                                                    u16* __restrict__ out, long n) {
    long i = (long)blockIdx.x * 256 + threadIdx.x;
    if (i < n) out[i] = f2bf(in[i]);
}

__global__ __launch_bounds__(256) void cvt_transpose(const float* __restrict__ in,
                                                     u16* __restrict__ out, int R, int C) {
    long i = (long)blockIdx.x * 256 + threadIdx.x;
    if (i < (long)R * C) {
        int c = (int)(i / R), r = (int)(i % R);
        out[i] = f2bf(in[(long)r * C + c]);
    }
}

// per-z transpose of 2048x2048 bf16
__global__ __launch_bounds__(256) void trans2048(const u16* __restrict__ in,
                                                 u16* __restrict__ out) {
    __shared__ u16 tile[64][65];
    const long z = blockIdx.z;
    const u16* I = in + z * (long)2048 * 2048;
    u16* O       = out + z * (long)2048 * 2048;
    const int bx = blockIdx.x * 64, by = blockIdx.y * 64;
    const int t = threadIdx.x, c = t & 63, r4 = t >> 6;
#pragma unroll
    for (int s = 0; s < 16; ++s) {
        int r = s * 4 + r4;
        tile[r][c] = I[(long)(by + r) * 2048 + bx + c];
    }
    __syncthreads();
#pragma unroll
    for (int s = 0; s < 16; ++s) {
        int r = s * 4 + r4;
        O[(long)(bx + r) * 2048 + by + c] = tile[c][r];
    }
}

// Fused dual softmax: A1 = softmax(S1); A2 = softmax(S2);
// Pre = 0.5*S1 + 0.75*S2 + 0.5*logaddexp(S1,S2)  (Pre may alias S1).
__global__ __launch_bounds__(256) void sm01(
    const u16* __restrict__ S1, const u16* __restrict__ S2,
    u16* __restrict__ A1, u16* __restrict__ A2, u16* __restrict__ Pre)
{
    const long row = blockIdx.x;
    const int t = threadIdx.x;
    s16x8 v1 = *(const s16x8*)(const void*)(S1 + row * 2048 + t * 8);
    s16x8 v2 = *(const s16x8*)(const void*)(S2 + row * 2048 + t * 8);
    float x1[8], x2[8];
#pragma unroll
    for (int e = 0; e < 8; ++e) { x1[e] = bf2f((u16)v1[e]); x2[e] = bf2f((u16)v2[e]); }
    float m1 = x1[0], m2 = x2[0];
#pragma unroll
    for (int e = 1; e < 8; ++e) { m1 = fmaxf(m1, x1[e]); m2 = fmaxf(m2, x2[e]); }
#pragma unroll
    for (int off = 32; off >= 1; off >>= 1) {
        m1 = fmaxf(m1, __shfl_xor(m1, off));
        m2 = fmaxf(m2, __shfl_xor(m2, off));
    }
    __shared__ float red[16];
    if ((t & 63) == 0) { red[t >> 6] = m1; red[4 + (t >> 6)] = m2; }
    __syncthreads();
    m1 = fmaxf(fmaxf(red[0], red[1]), fmaxf(red[2], red[3]));
    m2 = fmaxf(fmaxf(red[4], red[5]), fmaxf(red[6], red[7]));
    float s1 = 0.f, s2 = 0.f, e1[8], e2[8];
#pragma unroll
    for (int e = 0; e < 8; ++e) {
        e1[e] = __expf(x1[e] - m1); s1 += e1[e];
        e2[e] = __expf(x2[e] - m2); s2 += e2[e];
    }
#pragma unroll
    for (int off = 32; off >= 1; off >>= 1) {
        s1 += __shfl_xor(s1, off);
        s2 += __shfl_xor(s2, off);
    }
    if ((t & 63) == 0) { red[8 + (t >> 6)] = s1; red[12 + (t >> 6)] = s2; }
    __syncthreads();
    s1 = red[8] + red[9] + red[10] + red[11];
    s2 = red[12] + red[13] + red[14] + red[15];
    const float i1 = 1.f / s1, i2 = 1.f / s2;
    s16x8 o1, o2, op;
#pragma unroll
    for (int e = 0; e < 8; ++e) {
        o1[e] = (short)f2bf(e1[e] * i1);
        o2[e] = (short)f2bf(e2[e] * i2);
        const float a = x1[e], b = x2[e];
        const float lae = fmaxf(a, b) + log1pf(__expf(-fabsf(a - b)));
        op[e] = (short)f2bf(0.5f * a + 0.75f * b + 0.5f * lae);
    }
    *(s16x8*)(void*)(A1  + row * 2048 + t * 8) = o1;
    *(s16x8*)(void*)(A2  + row * 2048 + t * 8) = o2;
    *(s16x8*)(void*)(Pre + row * 2048 + t * 8) = op;
}

// One block per row: A = softmax(S)  (final mix softmax)
__global__ __launch_bounds__(256) void row_softmax_bf(
    const u16* __restrict__ S, u16* __restrict__ A)
{
    const long row = blockIdx.x;
    const int t = threadIdx.x;
    s16x8 xv = *(const s16x8*)(const void*)(S + row * 2048 + t * 8);
    float x[8];
#pragma unroll
    for (int e = 0; e < 8; ++e) x[e] = bf2f((u16)xv[e]);
    float m = x[0];
#pragma unroll
    for (int e = 1; e < 8; ++e) m = fmaxf(m, x[e]);
#pragma unroll
    for (int off = 32; off >= 1; off >>= 1) m = fmaxf(m, __shfl_xor(m, off));
    __shared__ float red[8];
    if ((t & 63) == 0) red[t >> 6] = m;
    __syncthreads();
    m = fmaxf(fmaxf(red[0], red[1]), fmaxf(red[2], red[3]));
    float s = 0.f, ee[8];
#pragma unroll
    for (int e = 0; e < 8; ++e) { ee[e] = __expf(x[e] - m); s += ee[e]; }
#pragma unroll
    for (int off = 32; off >= 1; off >>= 1) s += __shfl_xor(s, off);
    if ((t & 63) == 0) red[4 + (t >> 6)] = s;
    __syncthreads();
    s = red[4] + red[5] + red[6] + red[7];
    const float inv = 1.f / s;
    s16x8 o;
#pragma unroll
    for (int e = 0; e < 8; ++e) o[e] = (short)f2bf(ee[e] * inv);
    *(s16x8*)(void*)(A + row * 2048 + t * 8) = o;
}

extern "C" void kernel_launch(void* const* d_in, const int* in_sizes, int n_in,
                              void* d_out, int out_size, void* d_ws, size_t ws_size,
                              hipStream_t stream) {
    const float* x  = (const float*)d_in[0];
    const float* W1 = (const float*)d_in[1];
    const float* W2 = (const float*)d_in[2];
    const float* Wp = (const float*)d_in[3];
    const float* ch = (const float*)d_in[4];

    const int Bq = 2, N = 2048, D = 512, dk = 64, Z = 16;
    const long NN = (long)N * N;
    const long ND = (long)N * dk;
    (void)in_sizes; (void)n_in; (void)out_size;

    size_t ws_avail = ws_size ? ws_size : (size_t)-1;

    char* w = (char*)d_ws;
    size_t off = 0;
    auto alc = [&](size_t bytes) -> void* {
        void* p = w + off;
        off += (bytes + 255) & ~(size_t)255;
        return p;
    };

    // ---- persistent (~36 MiB) ----
    u16* xb   = (u16*)alc((long)Bq * N * D * 2);
    u16* W1t  = (u16*)alc((long)3 * D * D * 2);
    u16* W2t  = (u16*)alc((long)3 * D * D * 2);
    u16* Wpt  = (u16*)alc((long)D * D * 2);
    u16* Q1   = (u16*)alc(Z * ND * 2);
    u16* K1   = (u16*)alc(Z * ND * 2);
    u16* V1t  = (u16*)alc(Z * ND * 2);
    u16* Q2   = (u16*)alc(Z * ND * 2);
    u16* K2   = (u16*)alc(Z * ND * 2);
    u16* V2t  = (u16*)alc(Z * ND * 2);
    u16* y    = (u16*)alc((long)Bq * N * D * 2);
    const size_t persist = off;

    // G=4: per-group live set (4z x 4 NxN bf16 = 128 MiB) + persistent fits the
    // 256 MiB Infinity Cache -> inter-kernel handoffs become L3 hits.
    const size_t perz = 4 * (size_t)(NN * 2) + 4096;
    int G = 4;
    while (G > 1 && persist + (size_t)G * perz + 65536 > ws_avail) G >>= 1;

    u16*  S1b = (u16*)alc((size_t)G * NN * 2);   // S1 -> Pre -> Smix
    u16*  S2b = (u16*)alc((size_t)G * NN * 2);   // S2 -> A2t
    u16*  A1b = (u16*)alc((size_t)G * NN * 2);   // A1 -> C2
    u16*  C1b = (u16*)alc((size_t)G * NN * 2);   // A2 -> C1 -> final A

    const dim3 blk(256);
    const float iscale = 0.125f;  // 1/sqrt(64)

    cvt_f32_bf16<<<(unsigned)(((long)Bq * N * D + 255) / 256), blk, 0, stream>>>(x, xb, (long)Bq * N * D);
    cvt_transpose<<<(3 * D * D + 255) / 256, blk, 0, stream>>>(W1, W1t, D, 3 * D);
    cvt_transpose<<<(3 * D * D + 255) / 256, blk, 0, stream>>>(W2, W2t, D, 3 * D);
    cvt_transpose<<<(D * D + 255) / 256, blk, 0, stream>>>(Wp, Wpt, D, D);

    gemm_nt<E_QKV><<<dim3(32, 12, 1), blk, 0, stream>>>(
        xb, W1t, 0L, 0L, D, D, Bq * N, 3 * D, D,
        nullptr, Q1, K1, V1t, 0L, 0, iscale);
    gemm_nt<E_QKV><<<dim3(32, 12, 1), blk, 0, stream>>>(
        xb, W2t, 0L, 0L, D, D, Bq * N, 3 * D, D,
        nullptr, Q2, K2, V2t, 0L, 0, iscale);

    for (int zb = 0; zb < Z; zb += G) {
        const u16* Q1z = Q1 + (long)zb * ND;
        const u16* K1z = K1 + (long)zb * ND;
        const u16* V1z = V1t + (long)zb * ND;
        const u16* Q2z = Q2 + (long)zb * ND;
        const u16* K2z = K2 + (long)zb * ND;
        const u16* V2z = V2t + (long)zb * ND;

        // S1 -> S1b ; S2 -> S2b  (bf16, scale folded into Q)
        gemm_nt<E_BF16><<<dim3(16, 16, G), blk, 0, stream>>>(
            Q1z, K1z, ND, ND, dk, dk, N, N, dk,
            nullptr, S1b, nullptr, nullptr, NN, N, 1.f);
        gemm_nt<E_BF16><<<dim3(16, 16, G), blk, 0, stream>>>(
            Q2z, K2z, ND, ND, dk, dk, N, N, dk,
            nullptr, S2b, nullptr, nullptr, NN, N, 1.f);

        // fused dual softmax: A1 -> A1b ; A2 -> C1b ; Pre -> S1b (in-place)
        sm01<<<G * N, blk, 0, stream>>>(S1b, S2b, A1b, C1b, S1b);

        // A2t: C1b(A2) -> S2b
        trans2048<<<dim3(32, 32, G), blk, 0, stream>>>(C1b, S2b);

        // C1 = A1 @ A2 -> C1b
        gemm256_nt<E_BF16><<<dim3(8, 8, G), dim3(512), 0, stream>>>(
            A1b, S2b, NN, NN, N, N, N,
            C1b, nullptr, nullptr, NN, N);
        // C2 = C1 @ A2 ; Smix = Pre + 0.5*log(C2+eps) -> S1b ; C2 -> A1b
        gemm256_nt<E_SMIX><<<dim3(8, 8, G), dim3(512), 0, stream>>>(
            C1b, S2b, NN, NN, N, N, N,
            S1b, A1b, S1b, NN, N);
        // A = softmax(Smix) -> C1b
        row_softmax_bf<<<G * N, blk, 0, stream>>>(S1b, C1b);

        // y = A@v1 + sigmoid(chain)*(C2@v2)  -> bf16 [B,N,D]
        gemm_y<<<dim3(32, 1, G), blk, 0, stream>>>(
            C1b, A1b, V1z, V2z, y, ch, zb);
    }

    // out = y @ Wproj   (f32)
    gemm_nt<E_F32><<<dim3(32, 4, 1), blk, 0, stream>>>(
        y, Wpt, 0L, 0L, D, D, Bq * N, D, D,
        (float*)d_out, nullptr, nullptr, nullptr, 0L, D, 1.f);
}